// Round 6
// baseline (284.882 us; speedup 1.0000x reference)
//
#include <hip/hip_runtime.h>
#include <hip/hip_bf16.h>
#include <math.h>

#define T_TOK 3072
#define HID   1024
#define NH    16
#define HD    64
#define KVSPLIT 4
#define KVCHUNK (T_TOK / KVSPLIT)   // 768
#define LOG2E 1.4426950408889634f

typedef __attribute__((ext_vector_type(8))) short bf16x8;
typedef __attribute__((ext_vector_type(4))) short bf16x4;
typedef __attribute__((ext_vector_type(4))) float f32x4;

static __device__ __forceinline__ unsigned short f2bf(float x) {
  __hip_bfloat16 h = __float2bfloat16(x);
  return __builtin_bit_cast(unsigned short, h);
}

// swizzled LDS short-index for a [rows][64 bf16] tile, row stride 128B.
static __device__ __forceinline__ int swz(int row, int cb) {
  return row * 64 + ((cb ^ ((row & 7) << 4)) >> 1);
}

// ---------------- elementwise fp32 -> bf16 ----------------
__global__ __launch_bounds__(256) void cvt_bf16(const float* __restrict__ in,
                                                unsigned short* __restrict__ out, int n) {
  int i = (blockIdx.x * 256 + threadIdx.x) * 4;
  if (i < n) {
    float4 v = *(const float4*)(in + i);
    ushort4 o;
    o.x = f2bf(v.x); o.y = f2bf(v.y); o.z = f2bf(v.z); o.w = f2bf(v.w);
    *(ushort4*)(out + i) = o;
  }
}

// ---------------- transpose + convert: out[C][R] = bf16(in[R][C]) ----------------
__global__ __launch_bounds__(256) void transpose_cvt(const float* __restrict__ in,
                                                     unsigned short* __restrict__ out,
                                                     int R, int C) {
  __shared__ float tile[32][33];
  int c0 = blockIdx.x * 32, r0 = blockIdx.y * 32;
  int tx = threadIdx.x & 31, ty = threadIdx.x >> 5; // ty 0..7
  #pragma unroll
  for (int i = 0; i < 32; i += 8)
    tile[ty + i][tx] = in[(size_t)(r0 + ty + i) * C + c0 + tx];
  __syncthreads();
  #pragma unroll
  for (int i = 0; i < 32; i += 8)
    out[(size_t)(c0 + ty + i) * R + r0 + tx] = f2bf(tile[tx][ty + i]);
}

// ---------------- RoPE cos/sin tables [T][32] ----------------
__global__ __launch_bounds__(256) void rope_table(const int* __restrict__ pos,
                                                  float* __restrict__ ctab,
                                                  float* __restrict__ stab) {
  int i = blockIdx.x * 256 + threadIdx.x;  // T*32
  int t = i >> 5, j = i & 31;
  float inv = expf(-(float)j * 0.28782313662425572f);  // 10000^(-j/32)
  float f = (float)pos[t] * inv;
  ctab[i] = cosf(f);
  stab[i] = sinf(f);
}

// ---------------- RoPE apply + split Q,K to [H][T][D] bf16 ----------------
// Q is pre-scaled by 0.125 * log2(e) so softmax runs in exp2 domain.
__global__ __launch_bounds__(256) void rope_split(const float* __restrict__ QKV,
                                                  const float* __restrict__ ctab,
                                                  const float* __restrict__ stab,
                                                  unsigned short* __restrict__ Qh,
                                                  unsigned short* __restrict__ Kh) {
  const float QSCL = 0.18033688011112042f;  // 0.125 * log2e
  int i = blockIdx.x * 256 + threadIdx.x;  // T*NH*32
  int j = i & 31, h = (i >> 5) & 15, t = i >> 9;
  size_t base = (size_t)t * (3 * HID) + h * HD + j;
  float c = ctab[t * 32 + j], s = stab[t * 32 + j];
  float q1 = QKV[base], q2 = QKV[base + 32];
  float k1 = QKV[base + HID], k2 = QKV[base + HID + 32];
  size_t ob = ((size_t)h * T_TOK + t) * HD + j;
  Qh[ob]      = f2bf((q1 * c - q2 * s) * QSCL);
  Qh[ob + 32] = f2bf((q2 * c + q1 * s) * QSCL);
  Kh[ob]      = f2bf(k1 * c - k2 * s);
  Kh[ob + 32] = f2bf(k2 * c + k1 * s);
}

// ---------------- V: QKV[:,2048+h*64+d] -> Vt[H][D][T] bf16 ----------------
__global__ __launch_bounds__(256) void v_transpose(const float* __restrict__ QKV,
                                                   unsigned short* __restrict__ Vt) {
  int h = blockIdx.y;
  int t0 = blockIdx.x * 64;
  __shared__ unsigned short lds[64][72];
  int tx = threadIdx.x & 63, ty = threadIdx.x >> 6;  // ty 0..3
  #pragma unroll
  for (int i = 0; i < 16; ++i) {
    int t = ty * 16 + i;
    lds[tx][t] = f2bf(QKV[(size_t)(t0 + t) * (3 * HID) + 2 * HID + h * HD + tx]);
  }
  __syncthreads();
  #pragma unroll
  for (int i = 0; i < 16; ++i) {
    int d = ty * 16 + i;
    Vt[((size_t)h * HD + d) * T_TOK + t0 + tx] = lds[d][tx];
  }
}

// ---------------- GEMM: C[M,N] f32 = A[M,K] bf16 x Bt[N,K] bf16 ----------------
__global__ __launch_bounds__(256) void gemm_bt(const unsigned short* __restrict__ A,
                                               const unsigned short* __restrict__ Bt,
                                               float* __restrict__ C,
                                               int M, int N, int K) {
  __shared__ unsigned short As[128 * 64];
  __shared__ unsigned short Bs[128 * 64];
  const int lane = threadIdx.x & 63;
  const int wv = threadIdx.x >> 6;
  const int wm = wv >> 1, wn = wv & 1;
  const int r = lane & 15, hi = lane >> 4;
  const int m0 = blockIdx.y * 128, n0 = blockIdx.x * 128;
  f32x4 acc[4][4] = {};
  for (int kt = 0; kt < K; kt += 64) {
    __syncthreads();
    #pragma unroll
    for (int i = 0; i < 4; ++i) {
      int o = (wv * 4 + i) * 1024 + lane * 16;  // byte offset into 16KB tile
      int row = o >> 7;                          // 128B per row (64 bf16)
      int col = (o & 127) >> 1;
      const unsigned short* ga = A + (size_t)(m0 + row) * K + kt + col;
      __builtin_amdgcn_global_load_lds(
          (const __attribute__((address_space(1))) unsigned int*)ga,
          (__attribute__((address_space(3))) unsigned int*)((char*)As + (wv * 4 + i) * 1024),
          16, 0, 0);
      const unsigned short* gb = Bt + (size_t)(n0 + row) * K + kt + col;
      __builtin_amdgcn_global_load_lds(
          (const __attribute__((address_space(1))) unsigned int*)gb,
          (__attribute__((address_space(3))) unsigned int*)((char*)Bs + (wv * 4 + i) * 1024),
          16, 0, 0);
    }
    __syncthreads();
    #pragma unroll
    for (int kk = 0; kk < 2; ++kk) {
      bf16x8 a[4], b[4];
      #pragma unroll
      for (int tm = 0; tm < 4; ++tm)
        a[tm] = *(const bf16x8*)&As[(wm * 64 + tm * 16 + r) * 64 + kk * 32 + hi * 8];
      #pragma unroll
      for (int tn = 0; tn < 4; ++tn)
        b[tn] = *(const bf16x8*)&Bs[(wn * 64 + tn * 16 + r) * 64 + kk * 32 + hi * 8];
      #pragma unroll
      for (int tm = 0; tm < 4; ++tm)
        #pragma unroll
        for (int tn = 0; tn < 4; ++tn)
          acc[tm][tn] = __builtin_amdgcn_mfma_f32_16x16x32_bf16(a[tm], b[tn], acc[tm][tn], 0, 0, 0);
    }
  }
  #pragma unroll
  for (int tm = 0; tm < 4; ++tm)
    #pragma unroll
    for (int tn = 0; tn < 4; ++tn) {
      int colg = n0 + wn * 64 + tn * 16 + r;
      int rowg = m0 + wm * 64 + tm * 16 + hi * 4;
      float* cp = C + (size_t)rowg * N + colg;
      #pragma unroll
      for (int j = 0; j < 4; ++j) cp[(size_t)j * N] = acc[tm][tn][j];
    }
}

// ---------------- flash attention core (templated for ablation) ----------------
// STAGE_EVERY=1: real kernel (R2-exact, best known 122us).
// STAGE_EVERY=0: ablation — K/V staged only on first tile; compute identical
// (reads stale-but-valid LDS). Isolates the per-tile gload_lds + vmcnt-drain cost.
template <int STAGE_EVERY>
__device__ __forceinline__ void flash_body(const unsigned short* __restrict__ Qh,
                                           const unsigned short* __restrict__ Kh,
                                           const unsigned short* __restrict__ Vt,
                                           const float* __restrict__ mask,
                                           float* __restrict__ Op,
                                           float* __restrict__ Mp,
                                           float* __restrict__ Lp) {
  const int NBLK = (T_TOK / 64) * NH * KVSPLIT;     // 3072, divisible by 8
  int id = blockIdx.x;
  int sid = (id & 7) * (NBLK / 8) + (id >> 3);      // bijective XCD chunking
  const int h = sid & 15;
  int t2 = sid >> 4;                                 // 0..191
  const int qx = t2 % (T_TOK / 64);
  const int z  = t2 / (T_TOK / 64);
  const int q0 = qx * 64;
  const int kv0 = z * KVCHUNK;

  __shared__ unsigned short Ks[64 * 64];
  __shared__ unsigned short Vs[64 * 64];
  const int lane = threadIdx.x & 63, wv = threadIdx.x >> 6;
  const int r = lane & 15, hi = lane >> 4;
  const int qrow = q0 + wv * 16 + r;
  const bf16x8 qf0 = *(const bf16x8*)(Qh + ((size_t)h * T_TOK + qrow) * HD + hi * 8);
  const bf16x8 qf1 = *(const bf16x8*)(Qh + ((size_t)h * T_TOK + qrow) * HD + 32 + hi * 8);
  f32x4 acc_o[4] = {};
  float m = -INFINITY, l = 0.f;

  const int ldrow = lane >> 3;                         // == dest row & 7
  const int colS  = ((lane & 7) * 16) ^ (ldrow << 4);  // source byte col
  const unsigned short* kga = Kh + ((size_t)h * T_TOK + wv * 16 + ldrow) * HD + (colS >> 1);
  const unsigned short* vga = Vt + ((size_t)h * HD + wv * 16 + ldrow) * T_TOK + (colS >> 1);
  char* ksd = (char*)Ks + wv * 2048;
  char* vsd = (char*)Vs + wv * 2048;
  const float* mrow = mask + (size_t)qrow * T_TOK;

  for (int s0 = kv0; s0 < kv0 + KVCHUNK; s0 += 64) {
    __syncthreads();  // previous tile's LDS reads complete
    if (STAGE_EVERY || s0 == kv0) {
      __builtin_amdgcn_global_load_lds(
          (const __attribute__((address_space(1))) unsigned int*)(kga + (size_t)s0 * HD),
          (__attribute__((address_space(3))) unsigned int*)ksd, 16, 0, 0);
      __builtin_amdgcn_global_load_lds(
          (const __attribute__((address_space(1))) unsigned int*)(kga + (size_t)s0 * HD + 8 * HD),
          (__attribute__((address_space(3))) unsigned int*)(ksd + 1024), 16, 0, 0);
      __builtin_amdgcn_global_load_lds(
          (const __attribute__((address_space(1))) unsigned int*)(vga + s0),
          (__attribute__((address_space(3))) unsigned int*)vsd, 16, 0, 0);
      __builtin_amdgcn_global_load_lds(
          (const __attribute__((address_space(1))) unsigned int*)(vga + s0 + 8 * T_TOK),
          (__attribute__((address_space(3))) unsigned int*)(vsd + 1024), 16, 0, 0);
    }
    // mask loads issue here; latency hides under the staging drain
    float4 mk[4];
    #pragma unroll
    for (int b = 0; b < 4; ++b) mk[b] = *(const float4*)(mrow + s0 + b * 16 + hi * 4);
    __syncthreads();  // vmcnt(0) drain -> LDS + mask ready

    // QK^T -> S^T[kv,q]; Q pre-scaled by 0.125*log2e, mask folded via fma
    float sv[16];
    __builtin_amdgcn_s_setprio(1);
    #pragma unroll
    for (int b = 0; b < 4; ++b) {
      bf16x8 kf0 = *(const bf16x8*)&Ks[swz(b * 16 + r, hi * 16)];
      bf16x8 kf1 = *(const bf16x8*)&Ks[swz(b * 16 + r, 64 + hi * 16)];
      f32x4 zf = {};
      zf = __builtin_amdgcn_mfma_f32_16x16x32_bf16(kf0, qf0, zf, 0, 0, 0);
      zf = __builtin_amdgcn_mfma_f32_16x16x32_bf16(kf1, qf1, zf, 0, 0, 0);
      sv[b * 4 + 0] = fmaf(mk[b].x, LOG2E, zf[0]);
      sv[b * 4 + 1] = fmaf(mk[b].y, LOG2E, zf[1]);
      sv[b * 4 + 2] = fmaf(mk[b].z, LOG2E, zf[2]);
      sv[b * 4 + 3] = fmaf(mk[b].w, LOG2E, zf[3]);
    }
    __builtin_amdgcn_s_setprio(0);

    // row max via max3 tree + 4-lane group reduce
    float t0 = fmaxf(fmaxf(sv[0], sv[1]), sv[2]);
    float t1 = fmaxf(fmaxf(sv[3], sv[4]), sv[5]);
    float t2m = fmaxf(fmaxf(sv[6], sv[7]), sv[8]);
    float t3 = fmaxf(fmaxf(sv[9], sv[10]), sv[11]);
    float t4 = fmaxf(fmaxf(sv[12], sv[13]), sv[14]);
    float pmax = fmaxf(fmaxf(fmaxf(t0, t1), t2m), fmaxf(fmaxf(t3, t4), sv[15]));
    pmax = fmaxf(pmax, __shfl_xor(pmax, 16));
    pmax = fmaxf(pmax, __shfl_xor(pmax, 32));

    // defer-max: only rescale when the running max grew by > 8 (log2 units)
    if (__any(pmax > m + 8.f)) {
      float mnew = fmaxf(m, pmax);
      float sc = __builtin_amdgcn_exp2f(m - mnew);
      m = mnew;
      l *= sc;
      float sc0 = __shfl(sc, hi * 4 + 0);
      float sc1 = __shfl(sc, hi * 4 + 1);
      float sc2 = __shfl(sc, hi * 4 + 2);
      float sc3 = __shfl(sc, hi * 4 + 3);
      #pragma unroll
      for (int d = 0; d < 4; ++d) {
        acc_o[d][0] *= sc0; acc_o[d][1] *= sc1;
        acc_o[d][2] *= sc2; acc_o[d][3] *= sc3;
      }
    }

    // P = exp2(sv - m), packed straight into K=16 A-fragments
    float ps = 0.f;
    bf16x4 pa[4];
    #pragma unroll
    for (int b = 0; b < 4; ++b) {
      bf16x4 t;
      #pragma unroll
      for (int j = 0; j < 4; ++j) {
        float p = __builtin_amdgcn_exp2f(sv[b * 4 + j] - m);
        ps += p;
        t[j] = (short)f2bf(p);
      }
      pa[b] = t;
    }
    ps += __shfl_xor(ps, 16);
    ps += __shfl_xor(ps, 32);
    l += ps;

    // PV: O[q,d] += P[q,kv] * V[kv,d] via 16 x mfma_16x16x16 (A = pa, in regs)
    __builtin_amdgcn_s_setprio(1);
    #pragma unroll
    for (int d = 0; d < 4; ++d)
      #pragma unroll
      for (int b = 0; b < 4; ++b) {
        bf16x4 vf = *(const bf16x4*)&Vs[swz(d * 16 + r, b * 32 + hi * 8)];
        acc_o[d] = __builtin_amdgcn_mfma_f32_16x16x16bf16_1k(pa[b], vf, acc_o[d], 0, 0, 0);
      }
    __builtin_amdgcn_s_setprio(0);
  }

  // epilogue: write unnormalized partials + (m,l) (m in log2 domain)
  #pragma unroll
  for (int d = 0; d < 4; ++d)
    #pragma unroll
    for (int j = 0; j < 4; ++j) {
      int trow = q0 + wv * 16 + hi * 4 + j;
      Op[(((size_t)z * T_TOK + trow) * NH + h) * HD + d * 16 + r] = acc_o[d][j];
    }
  if (hi == 0) {
    size_t mi = ((size_t)z * T_TOK + qrow) * NH + h;
    Mp[mi] = m;
    Lp[mi] = l;
  }
}

__global__ __launch_bounds__(256) void flash_attn(const unsigned short* __restrict__ Qh,
                                                  const unsigned short* __restrict__ Kh,
                                                  const unsigned short* __restrict__ Vt,
                                                  const float* __restrict__ mask,
                                                  float* __restrict__ Op,
                                                  float* __restrict__ Mp,
                                                  float* __restrict__ Lp) {
  flash_body<1>(Qh, Kh, Vt, mask, Op, Mp, Lp);
}

// ABLATION probe: identical compute, staging only on tile 0. Writes to buffers
// that are dead by the time it runs (after combine). Diagnostic only.
__global__ __launch_bounds__(256) void flash_ablate_nostage(const unsigned short* __restrict__ Qh,
                                                            const unsigned short* __restrict__ Kh,
                                                            const unsigned short* __restrict__ Vt,
                                                            const float* __restrict__ mask,
                                                            float* __restrict__ Op,
                                                            float* __restrict__ Mp,
                                                            float* __restrict__ Lp) {
  flash_body<0>(Qh, Kh, Vt, mask, Op, Mp, Lp);
}

// ---------------- combine KV-split partials (log2-domain maxes) ----------------
__global__ __launch_bounds__(256) void combine(const float* __restrict__ Op,
                                               const float* __restrict__ Mp,
                                               const float* __restrict__ Lp,
                                               unsigned short* __restrict__ Ob) {
  int idx = blockIdx.x * 256 + threadIdx.x;  // T*256 total (4 floats each)
  int t = idx >> 8;
  int q4 = (idx & 255) * 4;  // within [HID): h*64 + d
  int h = q4 >> 6, d = q4 & 63;
  float mz[KVSPLIT], lz[KVSPLIT];
  float ms = -INFINITY;
  #pragma unroll
  for (int zz = 0; zz < KVSPLIT; ++zz) {
    size_t mi = ((size_t)zz * T_TOK + t) * NH + h;
    mz[zz] = Mp[mi];
    lz[zz] = Lp[mi];
    ms = fmaxf(ms, mz[zz]);
  }
  float lsum = 0.f;
  float w[KVSPLIT];
  #pragma unroll
  for (int zz = 0; zz < KVSPLIT; ++zz) {
    w[zz] = __builtin_amdgcn_exp2f(mz[zz] - ms);
    lsum += lz[zz] * w[zz];
  }
  float4 o = {0.f, 0.f, 0.f, 0.f};
  #pragma unroll
  for (int zz = 0; zz < KVSPLIT; ++zz) {
    float4 p = *(const float4*)(Op + (((size_t)zz * T_TOK + t) * NH + h) * HD + d);
    o.x += p.x * w[zz]; o.y += p.y * w[zz];
    o.z += p.z * w[zz]; o.w += p.w * w[zz];
  }
  float inv = 1.f / lsum;
  ushort4 ob;
  ob.x = f2bf(o.x * inv); ob.y = f2bf(o.y * inv);
  ob.z = f2bf(o.z * inv); ob.w = f2bf(o.w * inv);
  *(ushort4*)(Ob + (size_t)t * HID + q4) = ob;
}

extern "C" void kernel_launch(void* const* d_in, const int* in_sizes, int n_in,
                              void* d_out, int out_size, void* d_ws, size_t ws_size,
                              hipStream_t stream) {
  const float* X    = (const float*)d_in[0];
  const float* Wqkv = (const float*)d_in[1];
  const float* Wo   = (const float*)d_in[2];
  const float* mask = (const float*)d_in[3];
  const int*   pos  = (const int*)d_in[4];
  float* out = (float*)d_out;

  char* ws = (char*)d_ws;
  size_t off = 0;
  auto alloc = [&](size_t bytes) {
    char* p = ws + off;
    off += (bytes + 255) & ~(size_t)255;
    return p;
  };
  unsigned short* Xb    = (unsigned short*)alloc((size_t)T_TOK * HID * 2);
  unsigned short* WqkvT = (unsigned short*)alloc((size_t)3 * HID * HID * 2);
  unsigned short* WoT   = (unsigned short*)alloc((size_t)HID * HID * 2);
  unsigned short* Qh    = (unsigned short*)alloc((size_t)NH * T_TOK * HD * 2);
  unsigned short* Kh    = (unsigned short*)alloc((size_t)NH * T_TOK * HD * 2);
  unsigned short* Vt    = (unsigned short*)alloc((size_t)NH * HD * T_TOK * 2);
  unsigned short* Ob    = (unsigned short*)alloc((size_t)T_TOK * HID * 2);
  float*          ctab  = (float*)alloc((size_t)T_TOK * 32 * 4);
  float*          stab  = (float*)alloc((size_t)T_TOK * 32 * 4);
  float*          Mp    = (float*)alloc((size_t)KVSPLIT * T_TOK * NH * 4);
  float*          Lp    = (float*)alloc((size_t)KVSPLIT * T_TOK * NH * 4);
  // REGION: QKV (f32 T x 3H) aliased with Opart (f32 KVSPLIT x T x HID).
  float*          QKV   = (float*)alloc((size_t)KVSPLIT * T_TOK * HID * 4);
  float*          Op    = QKV;

  cvt_bf16<<<(T_TOK * HID / 4 + 255) / 256, 256, 0, stream>>>(X, Xb, T_TOK * HID);
  transpose_cvt<<<dim3(3 * HID / 32, HID / 32), 256, 0, stream>>>(Wqkv, WqkvT, HID, 3 * HID);
  transpose_cvt<<<dim3(HID / 32, HID / 32), 256, 0, stream>>>(Wo, WoT, HID, HID);
  rope_table<<<T_TOK * 32 / 256, 256, 0, stream>>>(pos, ctab, stab);

  gemm_bt<<<dim3(3 * HID / 128, T_TOK / 128), 256, 0, stream>>>(Xb, WqkvT, QKV, T_TOK, 3 * HID, HID);

  rope_split<<<T_TOK * NH * 32 / 256, 256, 0, stream>>>(QKV, ctab, stab, Qh, Kh);
  v_transpose<<<dim3(T_TOK / 64, NH), 256, 0, stream>>>(QKV, Vt);

  flash_attn<<<dim3((T_TOK / 64) * NH * KVSPLIT), 256, 0, stream>>>(Qh, Kh, Vt, mask, Op, Mp, Lp);
  combine<<<T_TOK, 256, 0, stream>>>(Op, Mp, Lp, Ob);

  gemm_bt<<<dim3(HID / 128, T_TOK / 128), 256, 0, stream>>>(Ob, WoT, out, T_TOK, HID, HID);

  // Diagnostic ablation (runs after Op/Mp/Lp are dead; does not affect d_out).
  flash_ablate_nostage<<<dim3((T_TOK / 64) * NH * KVSPLIT), 256, 0, stream>>>(Qh, Kh, Vt, mask, Op, Mp, Lp);
}

// Round 7
// 192.651 us; speedup vs baseline: 1.4787x; 1.4787x over previous
//
#include <hip/hip_runtime.h>
#include <hip/hip_bf16.h>
#include <math.h>

#define T_TOK 3072
#define HID   1024
#define NH    16
#define HD    64
#define KVSPLIT 2
#define KVCHUNK (T_TOK / KVSPLIT)   // 1536
#define NQX (T_TOK / 64)            // 48
#define LOG2E 1.4426950408889634f

typedef __attribute__((ext_vector_type(8))) short bf16x8;
typedef __attribute__((ext_vector_type(4))) short bf16x4;
typedef __attribute__((ext_vector_type(4))) float f32x4;

#define VMCNT(n) asm volatile("s_waitcnt vmcnt(" #n ")" ::: "memory")
#define SB() __builtin_amdgcn_sched_barrier(0)

static __device__ __forceinline__ unsigned short f2bf(float x) {
  __hip_bfloat16 h = __float2bfloat16(x);
  return __builtin_bit_cast(unsigned short, h);
}

// swizzled LDS short-index for a [rows][64 bf16] tile, row stride 128B.
static __device__ __forceinline__ int swz(int row, int cb) {
  return row * 64 + ((cb ^ ((row & 7) << 4)) >> 1);
}

// ---------------- elementwise fp32 -> bf16 ----------------
__global__ __launch_bounds__(256) void cvt_bf16(const float* __restrict__ in,
                                                unsigned short* __restrict__ out, int n) {
  int i = (blockIdx.x * 256 + threadIdx.x) * 4;
  if (i < n) {
    float4 v = *(const float4*)(in + i);
    ushort4 o;
    o.x = f2bf(v.x); o.y = f2bf(v.y); o.z = f2bf(v.z); o.w = f2bf(v.w);
    *(ushort4*)(out + i) = o;
  }
}

// ---------------- transpose + convert: out[C][R] = bf16(in[R][C]) ----------------
__global__ __launch_bounds__(256) void transpose_cvt(const float* __restrict__ in,
                                                     unsigned short* __restrict__ out,
                                                     int R, int C) {
  __shared__ float tile[32][33];
  int c0 = blockIdx.x * 32, r0 = blockIdx.y * 32;
  int tx = threadIdx.x & 31, ty = threadIdx.x >> 5; // ty 0..7
  #pragma unroll
  for (int i = 0; i < 32; i += 8)
    tile[ty + i][tx] = in[(size_t)(r0 + ty + i) * C + c0 + tx];
  __syncthreads();
  #pragma unroll
  for (int i = 0; i < 32; i += 8)
    out[(size_t)(c0 + ty + i) * R + r0 + tx] = f2bf(tile[tx][ty + i]);
}

// ---------------- RoPE cos/sin tables [T][32] ----------------
__global__ __launch_bounds__(256) void rope_table(const int* __restrict__ pos,
                                                  float* __restrict__ ctab,
                                                  float* __restrict__ stab) {
  int i = blockIdx.x * 256 + threadIdx.x;  // T*32
  int t = i >> 5, j = i & 31;
  float inv = expf(-(float)j * 0.28782313662425572f);  // 10000^(-j/32)
  float f = (float)pos[t] * inv;
  ctab[i] = cosf(f);
  stab[i] = sinf(f);
}

// ---------------- RoPE apply + split Q,K to [H][T][D] bf16 ----------------
// Q is pre-scaled by 0.125 * log2(e) so softmax runs in exp2 domain.
__global__ __launch_bounds__(256) void rope_split(const float* __restrict__ QKV,
                                                  const float* __restrict__ ctab,
                                                  const float* __restrict__ stab,
                                                  unsigned short* __restrict__ Qh,
                                                  unsigned short* __restrict__ Kh) {
  const float QSCL = 0.18033688011112042f;  // 0.125 * log2e
  int i = blockIdx.x * 256 + threadIdx.x;  // T*NH*32
  int j = i & 31, h = (i >> 5) & 15, t = i >> 9;
  size_t base = (size_t)t * (3 * HID) + h * HD + j;
  float c = ctab[t * 32 + j], s = stab[t * 32 + j];
  float q1 = QKV[base], q2 = QKV[base + 32];
  float k1 = QKV[base + HID], k2 = QKV[base + HID + 32];
  size_t ob = ((size_t)h * T_TOK + t) * HD + j;
  Qh[ob]      = f2bf((q1 * c - q2 * s) * QSCL);
  Qh[ob + 32] = f2bf((q2 * c + q1 * s) * QSCL);
  Kh[ob]      = f2bf(k1 * c - k2 * s);
  Kh[ob + 32] = f2bf(k2 * c + k1 * s);
}

// ---------------- V: QKV[:,2048+h*64+d] -> Vt[H][D][T] bf16 ----------------
__global__ __launch_bounds__(256) void v_transpose(const float* __restrict__ QKV,
                                                   unsigned short* __restrict__ Vt) {
  int h = blockIdx.y;
  int t0 = blockIdx.x * 64;
  __shared__ unsigned short lds[64][72];
  int tx = threadIdx.x & 63, ty = threadIdx.x >> 6;  // ty 0..3
  #pragma unroll
  for (int i = 0; i < 16; ++i) {
    int t = ty * 16 + i;
    lds[tx][t] = f2bf(QKV[(size_t)(t0 + t) * (3 * HID) + 2 * HID + h * HD + tx]);
  }
  __syncthreads();
  #pragma unroll
  for (int i = 0; i < 16; ++i) {
    int d = ty * 16 + i;
    Vt[((size_t)h * HD + d) * T_TOK + t0 + tx] = lds[d][tx];
  }
}

// ---------------- per-(q-tile, kv-chunk) mask nonzero flags ----------------
__global__ __launch_bounds__(1024) void mask_flags(const float* __restrict__ mask,
                                                   int* __restrict__ flags) {
  int qx = blockIdx.x, z = blockIdx.y;
  const float* base = mask + (size_t)(qx * 64) * T_TOK + z * KVCHUNK;
  int any = 0;
  const int NC4 = KVCHUNK / 4;  // 384
  for (int i = threadIdx.x; i < 64 * NC4; i += 1024) {
    int row = i / NC4, c = i - row * NC4;
    float4 v = *(const float4*)(base + (size_t)row * T_TOK + c * 4);
    any |= (v.x != 0.f) | (v.y != 0.f) | (v.z != 0.f) | (v.w != 0.f);
  }
  __shared__ int s;
  if (threadIdx.x == 0) s = 0;
  __syncthreads();
  if (__any(any) && (threadIdx.x & 63) == 0) s = 1;  // benign same-value race
  __syncthreads();
  if (threadIdx.x == 0) flags[z * NQX + qx] = s;
}

// ---------------- GEMM: C[M,N] f32 = A[M,K] bf16 x Bt[N,K] bf16 ----------------
__global__ __launch_bounds__(256) void gemm_bt(const unsigned short* __restrict__ A,
                                               const unsigned short* __restrict__ Bt,
                                               float* __restrict__ C,
                                               int M, int N, int K) {
  __shared__ unsigned short As[128 * 64];
  __shared__ unsigned short Bs[128 * 64];
  const int lane = threadIdx.x & 63;
  const int wv = threadIdx.x >> 6;
  const int wm = wv >> 1, wn = wv & 1;
  const int r = lane & 15, hi = lane >> 4;
  const int m0 = blockIdx.y * 128, n0 = blockIdx.x * 128;
  f32x4 acc[4][4] = {};
  for (int kt = 0; kt < K; kt += 64) {
    __syncthreads();
    #pragma unroll
    for (int i = 0; i < 4; ++i) {
      int o = (wv * 4 + i) * 1024 + lane * 16;  // byte offset into 16KB tile
      int row = o >> 7;                          // 128B per row (64 bf16)
      int col = (o & 127) >> 1;
      const unsigned short* ga = A + (size_t)(m0 + row) * K + kt + col;
      __builtin_amdgcn_global_load_lds(
          (const __attribute__((address_space(1))) unsigned int*)ga,
          (__attribute__((address_space(3))) unsigned int*)((char*)As + (wv * 4 + i) * 1024),
          16, 0, 0);
      const unsigned short* gb = Bt + (size_t)(n0 + row) * K + kt + col;
      __builtin_amdgcn_global_load_lds(
          (const __attribute__((address_space(1))) unsigned int*)gb,
          (__attribute__((address_space(3))) unsigned int*)((char*)Bs + (wv * 4 + i) * 1024),
          16, 0, 0);
    }
    __syncthreads();
    #pragma unroll
    for (int kk = 0; kk < 2; ++kk) {
      bf16x8 a[4], b[4];
      #pragma unroll
      for (int tm = 0; tm < 4; ++tm)
        a[tm] = *(const bf16x8*)&As[(wm * 64 + tm * 16 + r) * 64 + kk * 32 + hi * 8];
      #pragma unroll
      for (int tn = 0; tn < 4; ++tn)
        b[tn] = *(const bf16x8*)&Bs[(wn * 64 + tn * 16 + r) * 64 + kk * 32 + hi * 8];
      #pragma unroll
      for (int tm = 0; tm < 4; ++tm)
        #pragma unroll
        for (int tn = 0; tn < 4; ++tn)
          acc[tm][tn] = __builtin_amdgcn_mfma_f32_16x16x32_bf16(a[tm], b[tn], acc[tm][tn], 0, 0, 0);
    }
  }
  #pragma unroll
  for (int tm = 0; tm < 4; ++tm)
    #pragma unroll
    for (int tn = 0; tn < 4; ++tn) {
      int colg = n0 + wn * 64 + tn * 16 + r;
      int rowg = m0 + wm * 64 + tm * 16 + hi * 4;
      float* cp = C + (size_t)rowg * N + colg;
      #pragma unroll
      for (int j = 0; j < 4; ++j) cp[(size_t)j * N] = acc[tm][tn][j];
    }
}

// ---------------- flash attention: counted-vmcnt double-buffer pipeline ----------------
// grid 1D (T/64)*NH*KVSPLIT, XCD-remapped. block 256 = 4 waves x 16 q-rows.
// LDS: Ks[2]+Vs[2] = 32KB. Steady state per tile:
//   stage(t+1 -> buf^1) ; s_waitcnt vmcnt(4) [wait tile t only] ; s_barrier ;
//   compute(buf[cur])   ; s_barrier
// Raw barriers (no __syncthreads vmcnt(0) drain) keep next-tile loads in flight.
// Mask handled via per-chunk nonzero flag: zero chunks take a lean loop with
// no mask loads (removes ~50MB gather); nonzero chunks use vmcnt(8) variant.
__global__ __launch_bounds__(256) void flash_attn(const unsigned short* __restrict__ Qh,
                                                  const unsigned short* __restrict__ Kh,
                                                  const unsigned short* __restrict__ Vt,
                                                  const float* __restrict__ mask,
                                                  const int* __restrict__ flags,
                                                  float* __restrict__ Op,
                                                  float* __restrict__ Mp,
                                                  float* __restrict__ Lp) {
  const int NBLK = NQX * NH * KVSPLIT;              // 1536, divisible by 8
  int id = blockIdx.x;
  int sid = (id & 7) * (NBLK / 8) + (id >> 3);      // bijective XCD chunking
  const int h = sid & 15;
  int t2 = sid >> 4;
  const int qx = t2 % NQX;
  const int z  = t2 / NQX;
  const int q0 = qx * 64;
  const int kv0 = z * KVCHUNK;
  const int NT = KVCHUNK / 64;                      // 24

  __shared__ unsigned short Ks[2][64 * 64];
  __shared__ unsigned short Vs[2][64 * 64];
  const int lane = threadIdx.x & 63, wv = threadIdx.x >> 6;
  const int r = lane & 15, hi = lane >> 4;
  const int qrow = q0 + wv * 16 + r;
  const bf16x8 qf0 = *(const bf16x8*)(Qh + ((size_t)h * T_TOK + qrow) * HD + hi * 8);
  const bf16x8 qf1 = *(const bf16x8*)(Qh + ((size_t)h * T_TOK + qrow) * HD + 32 + hi * 8);
  f32x4 acc_o[4] = {};
  float m = -INFINITY, l = 0.f;

  const int ldrow = lane >> 3;                         // dest row & 7
  const int colS  = ((lane & 7) * 16) ^ (ldrow << 4);  // pre-swizzled source byte col
  const unsigned short* kga = Kh + ((size_t)h * T_TOK + wv * 16 + ldrow) * HD + (colS >> 1);
  const unsigned short* vga = Vt + ((size_t)h * HD + wv * 16 + ldrow) * T_TOK + (colS >> 1);
  char* ksd = (char*)&Ks[0][0] + wv * 2048;
  char* vsd = (char*)&Vs[0][0] + wv * 2048;
  const float* mrow = mask + (size_t)qrow * T_TOK;
  const int hasmask = flags[z * NQX + qx];

  auto stage = [&](int buf, int s0) {
    __builtin_amdgcn_global_load_lds(
        (const __attribute__((address_space(1))) unsigned int*)(kga + (size_t)s0 * HD),
        (__attribute__((address_space(3))) unsigned int*)(ksd + buf * 8192), 16, 0, 0);
    __builtin_amdgcn_global_load_lds(
        (const __attribute__((address_space(1))) unsigned int*)(kga + (size_t)s0 * HD + 8 * HD),
        (__attribute__((address_space(3))) unsigned int*)(ksd + buf * 8192 + 1024), 16, 0, 0);
    __builtin_amdgcn_global_load_lds(
        (const __attribute__((address_space(1))) unsigned int*)(vga + s0),
        (__attribute__((address_space(3))) unsigned int*)(vsd + buf * 8192), 16, 0, 0);
    __builtin_amdgcn_global_load_lds(
        (const __attribute__((address_space(1))) unsigned int*)(vga + s0 + 8 * T_TOK),
        (__attribute__((address_space(3))) unsigned int*)(vsd + buf * 8192 + 1024), 16, 0, 0);
  };

  float4 mk[4];
  // tile compute; usemask resolved at inline time (uniform per block)
  auto tilecomp = [&](int cur, int s0, bool usemask) {
    float sv[16];
    __builtin_amdgcn_s_setprio(1);
    #pragma unroll
    for (int b = 0; b < 4; ++b) {
      bf16x8 kf0 = *(const bf16x8*)&Ks[cur][swz(b * 16 + r, hi * 16)];
      bf16x8 kf1 = *(const bf16x8*)&Ks[cur][swz(b * 16 + r, 64 + hi * 16)];
      f32x4 zf = {};
      zf = __builtin_amdgcn_mfma_f32_16x16x32_bf16(kf0, qf0, zf, 0, 0, 0);
      zf = __builtin_amdgcn_mfma_f32_16x16x32_bf16(kf1, qf1, zf, 0, 0, 0);
      if (usemask) {
        sv[b * 4 + 0] = fmaf(mk[b].x, LOG2E, zf[0]);
        sv[b * 4 + 1] = fmaf(mk[b].y, LOG2E, zf[1]);
        sv[b * 4 + 2] = fmaf(mk[b].z, LOG2E, zf[2]);
        sv[b * 4 + 3] = fmaf(mk[b].w, LOG2E, zf[3]);
      } else {
        sv[b * 4 + 0] = zf[0]; sv[b * 4 + 1] = zf[1];
        sv[b * 4 + 2] = zf[2]; sv[b * 4 + 3] = zf[3];
      }
    }
    __builtin_amdgcn_s_setprio(0);

    float t0 = fmaxf(fmaxf(sv[0], sv[1]), sv[2]);
    float t1 = fmaxf(fmaxf(sv[3], sv[4]), sv[5]);
    float t2m = fmaxf(fmaxf(sv[6], sv[7]), sv[8]);
    float t3 = fmaxf(fmaxf(sv[9], sv[10]), sv[11]);
    float t4 = fmaxf(fmaxf(sv[12], sv[13]), sv[14]);
    float pmax = fmaxf(fmaxf(fmaxf(t0, t1), t2m), fmaxf(fmaxf(t3, t4), sv[15]));
    pmax = fmaxf(pmax, __shfl_xor(pmax, 16));
    pmax = fmaxf(pmax, __shfl_xor(pmax, 32));

    if (__any(pmax > m + 8.f)) {
      float mnew = fmaxf(m, pmax);
      float sc = __builtin_amdgcn_exp2f(m - mnew);
      m = mnew;
      l *= sc;
      float sc0 = __shfl(sc, hi * 4 + 0);
      float sc1 = __shfl(sc, hi * 4 + 1);
      float sc2 = __shfl(sc, hi * 4 + 2);
      float sc3 = __shfl(sc, hi * 4 + 3);
      #pragma unroll
      for (int d = 0; d < 4; ++d) {
        acc_o[d][0] *= sc0; acc_o[d][1] *= sc1;
        acc_o[d][2] *= sc2; acc_o[d][3] *= sc3;
      }
    }

    float ps = 0.f;
    bf16x4 pa[4];
    #pragma unroll
    for (int b = 0; b < 4; ++b) {
      bf16x4 t;
      #pragma unroll
      for (int j = 0; j < 4; ++j) {
        float p = __builtin_amdgcn_exp2f(sv[b * 4 + j] - m);
        ps += p;
        t[j] = (short)f2bf(p);
      }
      pa[b] = t;
    }
    ps += __shfl_xor(ps, 16);
    ps += __shfl_xor(ps, 32);
    l += ps;

    __builtin_amdgcn_s_setprio(1);
    #pragma unroll
    for (int d = 0; d < 4; ++d)
      #pragma unroll
      for (int b = 0; b < 4; ++b) {
        bf16x4 vf = *(const bf16x4*)&Vs[cur][swz(d * 16 + r, b * 32 + hi * 8)];
        acc_o[d] = __builtin_amdgcn_mfma_f32_16x16x16bf16_1k(pa[b], vf, acc_o[d], 0, 0, 0);
      }
    __builtin_amdgcn_s_setprio(0);
  };

  stage(0, kv0);  // prologue: tile 0 in flight

  if (hasmask) {
    for (int it = 0; it < NT - 1; ++it) {
      const int s0 = kv0 + it * 64;
      #pragma unroll
      for (int b = 0; b < 4; ++b) mk[b] = *(const float4*)(mrow + s0 + b * 16 + hi * 4);
      stage((it + 1) & 1, s0 + 64);
      VMCNT(8);            // wait tile it's 4 stage loads only
      SB();
      __builtin_amdgcn_s_barrier();
      SB();
      tilecomp(it & 1, s0, true);
      __builtin_amdgcn_s_barrier();
    }
    const int s0 = kv0 + (NT - 1) * 64;
    #pragma unroll
    for (int b = 0; b < 4; ++b) mk[b] = *(const float4*)(mrow + s0 + b * 16 + hi * 4);
    VMCNT(4);
    SB();
    __builtin_amdgcn_s_barrier();
    SB();
    tilecomp((NT - 1) & 1, s0, true);
  } else {
    for (int it = 0; it < NT - 1; ++it) {
      const int s0 = kv0 + it * 64;
      stage((it + 1) & 1, s0 + 64);
      VMCNT(4);            // wait tile it's 4 stage loads only
      SB();
      __builtin_amdgcn_s_barrier();
      SB();
      tilecomp(it & 1, s0, false);
      __builtin_amdgcn_s_barrier();
    }
    const int s0 = kv0 + (NT - 1) * 64;
    VMCNT(0);
    SB();
    __builtin_amdgcn_s_barrier();
    SB();
    tilecomp((NT - 1) & 1, s0, false);
  }

  // epilogue: write unnormalized partials + (m,l) (m in log2 domain)
  #pragma unroll
  for (int d = 0; d < 4; ++d)
    #pragma unroll
    for (int j = 0; j < 4; ++j) {
      int trow = q0 + wv * 16 + hi * 4 + j;
      Op[(((size_t)z * T_TOK + trow) * NH + h) * HD + d * 16 + r] = acc_o[d][j];
    }
  if (hi == 0) {
    size_t mi = ((size_t)z * T_TOK + qrow) * NH + h;
    Mp[mi] = m;
    Lp[mi] = l;
  }
}

// ---------------- combine KV-split partials (log2-domain maxes) ----------------
__global__ __launch_bounds__(256) void combine(const float* __restrict__ Op,
                                               const float* __restrict__ Mp,
                                               const float* __restrict__ Lp,
                                               unsigned short* __restrict__ Ob) {
  int idx = blockIdx.x * 256 + threadIdx.x;  // T*256 total (4 floats each)
  int t = idx >> 8;
  int q4 = (idx & 255) * 4;  // within [HID): h*64 + d
  int h = q4 >> 6, d = q4 & 63;
  float mz[KVSPLIT], lz[KVSPLIT];
  float ms = -INFINITY;
  #pragma unroll
  for (int zz = 0; zz < KVSPLIT; ++zz) {
    size_t mi = ((size_t)zz * T_TOK + t) * NH + h;
    mz[zz] = Mp[mi];
    lz[zz] = Lp[mi];
    ms = fmaxf(ms, mz[zz]);
  }
  float lsum = 0.f;
  float w[KVSPLIT];
  #pragma unroll
  for (int zz = 0; zz < KVSPLIT; ++zz) {
    w[zz] = __builtin_amdgcn_exp2f(mz[zz] - ms);
    lsum += lz[zz] * w[zz];
  }
  float4 o = {0.f, 0.f, 0.f, 0.f};
  #pragma unroll
  for (int zz = 0; zz < KVSPLIT; ++zz) {
    float4 p = *(const float4*)(Op + (((size_t)zz * T_TOK + t) * NH + h) * HD + d);
    o.x += p.x * w[zz]; o.y += p.y * w[zz];
    o.z += p.z * w[zz]; o.w += p.w * w[zz];
  }
  float inv = 1.f / lsum;
  ushort4 ob;
  ob.x = f2bf(o.x * inv); ob.y = f2bf(o.y * inv);
  ob.z = f2bf(o.z * inv); ob.w = f2bf(o.w * inv);
  *(ushort4*)(Ob + (size_t)t * HID + q4) = ob;
}

extern "C" void kernel_launch(void* const* d_in, const int* in_sizes, int n_in,
                              void* d_out, int out_size, void* d_ws, size_t ws_size,
                              hipStream_t stream) {
  const float* X    = (const float*)d_in[0];
  const float* Wqkv = (const float*)d_in[1];
  const float* Wo   = (const float*)d_in[2];
  const float* mask = (const float*)d_in[3];
  const int*   pos  = (const int*)d_in[4];
  float* out = (float*)d_out;

  char* ws = (char*)d_ws;
  size_t off = 0;
  auto alloc = [&](size_t bytes) {
    char* p = ws + off;
    off += (bytes + 255) & ~(size_t)255;
    return p;
  };
  unsigned short* Xb    = (unsigned short*)alloc((size_t)T_TOK * HID * 2);
  unsigned short* WqkvT = (unsigned short*)alloc((size_t)3 * HID * HID * 2);
  unsigned short* WoT   = (unsigned short*)alloc((size_t)HID * HID * 2);
  unsigned short* Qh    = (unsigned short*)alloc((size_t)NH * T_TOK * HD * 2);
  unsigned short* Kh    = (unsigned short*)alloc((size_t)NH * T_TOK * HD * 2);
  unsigned short* Vt    = (unsigned short*)alloc((size_t)NH * HD * T_TOK * 2);
  unsigned short* Ob    = (unsigned short*)alloc((size_t)T_TOK * HID * 2);
  float*          ctab  = (float*)alloc((size_t)T_TOK * 32 * 4);
  float*          stab  = (float*)alloc((size_t)T_TOK * 32 * 4);
  float*          Mp    = (float*)alloc((size_t)KVSPLIT * T_TOK * NH * 4);
  float*          Lp    = (float*)alloc((size_t)KVSPLIT * T_TOK * NH * 4);
  int*            flags = (int*)alloc((size_t)KVSPLIT * NQX * 4);
  // REGION: QKV (f32 T x 3H = 37.75MB) aliased with Opart (f32 KVSPLIT x T x HID = 25.2MB).
  // QKV is dead once rope_split + v_transpose complete, before flash_attn writes Op.
  float*          QKV   = (float*)alloc((size_t)T_TOK * 3 * HID * 4);
  float*          Op    = QKV;

  cvt_bf16<<<(T_TOK * HID / 4 + 255) / 256, 256, 0, stream>>>(X, Xb, T_TOK * HID);
  transpose_cvt<<<dim3(3 * HID / 32, HID / 32), 256, 0, stream>>>(Wqkv, WqkvT, HID, 3 * HID);
  transpose_cvt<<<dim3(HID / 32, HID / 32), 256, 0, stream>>>(Wo, WoT, HID, HID);
  rope_table<<<T_TOK * 32 / 256, 256, 0, stream>>>(pos, ctab, stab);
  mask_flags<<<dim3(NQX, KVSPLIT), 1024, 0, stream>>>(mask, flags);

  gemm_bt<<<dim3(3 * HID / 128, T_TOK / 128), 256, 0, stream>>>(Xb, WqkvT, QKV, T_TOK, 3 * HID, HID);

  rope_split<<<T_TOK * NH * 32 / 256, 256, 0, stream>>>(QKV, ctab, stab, Qh, Kh);
  v_transpose<<<dim3(T_TOK / 64, NH), 256, 0, stream>>>(QKV, Vt);

  flash_attn<<<dim3(NQX * NH * KVSPLIT), 256, 0, stream>>>(Qh, Kh, Vt, mask, flags, Op, Mp, Lp);
  combine<<<T_TOK, 256, 0, stream>>>(Op, Mp, Lp, Ob);

  gemm_bt<<<dim3(HID / 128, T_TOK / 128), 256, 0, stream>>>(Ob, WoT, out, T_TOK, HID, HID);
}

// Round 8
// 191.141 us; speedup vs baseline: 1.4904x; 1.0079x over previous
//
#include <hip/hip_runtime.h>
#include <hip/hip_bf16.h>
#include <math.h>

#define T_TOK 3072
#define HID   1024
#define NH    16
#define HD    64
#define KVSPLIT 4
#define KVCHUNK (T_TOK / KVSPLIT)   // 768
#define NQB (T_TOK / 128)           // 24 q-tiles of 128 rows
#define LOG2E 1.4426950408889634f

typedef __attribute__((ext_vector_type(8))) short bf16x8;
typedef __attribute__((ext_vector_type(4))) float f32x4;
typedef __attribute__((ext_vector_type(16))) float f32x16;
typedef __attribute__((ext_vector_type(4))) unsigned int u32x4;

#define VMCNT(n) asm volatile("s_waitcnt vmcnt(" #n ")" ::: "memory")
#define SB() __builtin_amdgcn_sched_barrier(0)

static __device__ __forceinline__ unsigned short f2bf(float x) {
  __hip_bfloat16 h = __float2bfloat16(x);
  return __builtin_bit_cast(unsigned short, h);
}

// swizzled LDS short-index for a [rows][64 bf16] tile, row stride 128B.
static __device__ __forceinline__ int swz(int row, int cb) {
  return row * 64 + ((cb ^ ((row & 7) << 4)) >> 1);
}

// ---------------- elementwise fp32 -> bf16 ----------------
__global__ __launch_bounds__(256) void cvt_bf16(const float* __restrict__ in,
                                                unsigned short* __restrict__ out, int n) {
  int i = (blockIdx.x * 256 + threadIdx.x) * 4;
  if (i < n) {
    float4 v = *(const float4*)(in + i);
    ushort4 o;
    o.x = f2bf(v.x); o.y = f2bf(v.y); o.z = f2bf(v.z); o.w = f2bf(v.w);
    *(ushort4*)(out + i) = o;
  }
}

// ---------------- transpose + convert: out[C][R] = bf16(in[R][C]) ----------------
__global__ __launch_bounds__(256) void transpose_cvt(const float* __restrict__ in,
                                                     unsigned short* __restrict__ out,
                                                     int R, int C) {
  __shared__ float tile[32][33];
  int c0 = blockIdx.x * 32, r0 = blockIdx.y * 32;
  int tx = threadIdx.x & 31, ty = threadIdx.x >> 5; // ty 0..7
  #pragma unroll
  for (int i = 0; i < 32; i += 8)
    tile[ty + i][tx] = in[(size_t)(r0 + ty + i) * C + c0 + tx];
  __syncthreads();
  #pragma unroll
  for (int i = 0; i < 32; i += 8)
    out[(size_t)(c0 + ty + i) * R + r0 + tx] = f2bf(tile[tx][ty + i]);
}

// ---------------- RoPE cos/sin tables [T][32] ----------------
__global__ __launch_bounds__(256) void rope_table(const int* __restrict__ pos,
                                                  float* __restrict__ ctab,
                                                  float* __restrict__ stab) {
  int i = blockIdx.x * 256 + threadIdx.x;  // T*32
  int t = i >> 5, j = i & 31;
  float inv = expf(-(float)j * 0.28782313662425572f);  // 10000^(-j/32)
  float f = (float)pos[t] * inv;
  ctab[i] = cosf(f);
  stab[i] = sinf(f);
}

// ---------------- RoPE apply + split Q,K to [H][T][D] bf16 ----------------
// Q is pre-scaled by 0.125 * log2(e) so softmax runs in exp2 domain.
__global__ __launch_bounds__(256) void rope_split(const float* __restrict__ QKV,
                                                  const float* __restrict__ ctab,
                                                  const float* __restrict__ stab,
                                                  unsigned short* __restrict__ Qh,
                                                  unsigned short* __restrict__ Kh) {
  const float QSCL = 0.18033688011112042f;  // 0.125 * log2e
  int i = blockIdx.x * 256 + threadIdx.x;  // T*NH*32
  int j = i & 31, h = (i >> 5) & 15, t = i >> 9;
  size_t base = (size_t)t * (3 * HID) + h * HD + j;
  float c = ctab[t * 32 + j], s = stab[t * 32 + j];
  float q1 = QKV[base], q2 = QKV[base + 32];
  float k1 = QKV[base + HID], k2 = QKV[base + HID + 32];
  size_t ob = ((size_t)h * T_TOK + t) * HD + j;
  Qh[ob]      = f2bf((q1 * c - q2 * s) * QSCL);
  Qh[ob + 32] = f2bf((q2 * c + q1 * s) * QSCL);
  Kh[ob]      = f2bf(k1 * c - k2 * s);
  Kh[ob + 32] = f2bf(k2 * c + k1 * s);
}

// ---------------- V: QKV[:,2048+h*64+d] -> Vt[H][D][T] bf16 ----------------
__global__ __launch_bounds__(256) void v_transpose(const float* __restrict__ QKV,
                                                   unsigned short* __restrict__ Vt) {
  int h = blockIdx.y;
  int t0 = blockIdx.x * 64;
  __shared__ unsigned short lds[64][72];
  int tx = threadIdx.x & 63, ty = threadIdx.x >> 6;  // ty 0..3
  #pragma unroll
  for (int i = 0; i < 16; ++i) {
    int t = ty * 16 + i;
    lds[tx][t] = f2bf(QKV[(size_t)(t0 + t) * (3 * HID) + 2 * HID + h * HD + tx]);
  }
  __syncthreads();
  #pragma unroll
  for (int i = 0; i < 16; ++i) {
    int d = ty * 16 + i;
    Vt[((size_t)h * HD + d) * T_TOK + t0 + tx] = lds[d][tx];
  }
}

// ---------------- per-(q-tile128, kv-chunk) mask nonzero flags ----------------
__global__ __launch_bounds__(1024) void mask_flags(const float* __restrict__ mask,
                                                   int* __restrict__ flags) {
  int qx = blockIdx.x, z = blockIdx.y;
  const float* base = mask + (size_t)(qx * 128) * T_TOK + z * KVCHUNK;
  int any = 0;
  const int NC4 = KVCHUNK / 4;  // 192
  for (int i = threadIdx.x; i < 128 * NC4; i += 1024) {
    int row = i / NC4, c = i - row * NC4;
    float4 v = *(const float4*)(base + (size_t)row * T_TOK + c * 4);
    any |= (v.x != 0.f) | (v.y != 0.f) | (v.z != 0.f) | (v.w != 0.f);
  }
  __shared__ int s;
  if (threadIdx.x == 0) s = 0;
  __syncthreads();
  if (__any(any) && (threadIdx.x & 63) == 0) s = 1;  // benign same-value race
  __syncthreads();
  if (threadIdx.x == 0) flags[z * NQB + qx] = s;
}

// ---------------- GEMM: C[M,N] f32 = A[M,K] bf16 x Bt[N,K] bf16 ----------------
__global__ __launch_bounds__(256) void gemm_bt(const unsigned short* __restrict__ A,
                                               const unsigned short* __restrict__ Bt,
                                               float* __restrict__ C,
                                               int M, int N, int K) {
  __shared__ unsigned short As[128 * 64];
  __shared__ unsigned short Bs[128 * 64];
  const int lane = threadIdx.x & 63;
  const int wv = threadIdx.x >> 6;
  const int wm = wv >> 1, wn = wv & 1;
  const int r = lane & 15, hi = lane >> 4;
  const int m0 = blockIdx.y * 128, n0 = blockIdx.x * 128;
  f32x4 acc[4][4] = {};
  for (int kt = 0; kt < K; kt += 64) {
    __syncthreads();
    #pragma unroll
    for (int i = 0; i < 4; ++i) {
      int o = (wv * 4 + i) * 1024 + lane * 16;  // byte offset into 16KB tile
      int row = o >> 7;                          // 128B per row (64 bf16)
      int col = (o & 127) >> 1;
      const unsigned short* ga = A + (size_t)(m0 + row) * K + kt + col;
      __builtin_amdgcn_global_load_lds(
          (const __attribute__((address_space(1))) unsigned int*)ga,
          (__attribute__((address_space(3))) unsigned int*)((char*)As + (wv * 4 + i) * 1024),
          16, 0, 0);
      const unsigned short* gb = Bt + (size_t)(n0 + row) * K + kt + col;
      __builtin_amdgcn_global_load_lds(
          (const __attribute__((address_space(1))) unsigned int*)gb,
          (__attribute__((address_space(3))) unsigned int*)((char*)Bs + (wv * 4 + i) * 1024),
          16, 0, 0);
    }
    __syncthreads();
    #pragma unroll
    for (int kk = 0; kk < 2; ++kk) {
      bf16x8 a[4], b[4];
      #pragma unroll
      for (int tm = 0; tm < 4; ++tm)
        a[tm] = *(const bf16x8*)&As[(wm * 64 + tm * 16 + r) * 64 + kk * 32 + hi * 8];
      #pragma unroll
      for (int tn = 0; tn < 4; ++tn)
        b[tn] = *(const bf16x8*)&Bs[(wn * 64 + tn * 16 + r) * 64 + kk * 32 + hi * 8];
      #pragma unroll
      for (int tm = 0; tm < 4; ++tm)
        #pragma unroll
        for (int tn = 0; tn < 4; ++tn)
          acc[tm][tn] = __builtin_amdgcn_mfma_f32_16x16x32_bf16(a[tm], b[tn], acc[tm][tn], 0, 0, 0);
    }
  }
  #pragma unroll
  for (int tm = 0; tm < 4; ++tm)
    #pragma unroll
    for (int tn = 0; tn < 4; ++tn) {
      int colg = n0 + wn * 64 + tn * 16 + r;
      int rowg = m0 + wm * 64 + tm * 16 + hi * 4;
      float* cp = C + (size_t)rowg * N + colg;
      #pragma unroll
      for (int j = 0; j < 4; ++j) cp[(size_t)j * N] = acc[tm][tn][j];
    }
}

// ---------------- flash attention: 32x32 MFMA, lane-owns-q softmax ----------------
// grid 1D NQB*NH*KVSPLIT, XCD-remapped. block 256 = 4 waves x 32 q-rows = 128 q.
// Swapped QK^T via mfma_32x32x16: S^T C-layout col=lane&31=q -> each lane holds
// 32 S values of ONE q-row => softmax reduce = local tree + ONE shfl_xor(32);
// rescale is lane-local (no broadcasts); l is a per-lane partial (reduced once).
// PV consumes P via 8 independent u32 shfl_xor(32) exchanges into B-fragments.
// Counted-vmcnt double-buffer pipeline identical to R6.
__global__ __launch_bounds__(256) void flash_attn(const unsigned short* __restrict__ Qh,
                                                  const unsigned short* __restrict__ Kh,
                                                  const unsigned short* __restrict__ Vt,
                                                  const float* __restrict__ mask,
                                                  const int* __restrict__ flags,
                                                  float* __restrict__ Op,
                                                  float* __restrict__ Mp,
                                                  float* __restrict__ Lp) {
  const int NBLK = NQB * NH * KVSPLIT;              // 1536, divisible by 8
  int id = blockIdx.x;
  int sid = (id & 7) * (NBLK / 8) + (id >> 3);      // bijective XCD chunking
  const int hh = sid & 15;
  int t2 = sid >> 4;
  const int qx = t2 % NQB;
  const int z  = t2 / NQB;
  const int q0 = qx * 128;
  const int kv0 = z * KVCHUNK;
  const int NT = KVCHUNK / 64;                      // 12

  __shared__ unsigned short Ks[2][64 * 64];
  __shared__ unsigned short Vs[2][64 * 64];
  const int lane = threadIdx.x & 63, wv = threadIdx.x >> 6;
  const int q31 = lane & 31, h2 = lane >> 5;
  const int qw = q0 + wv * 32 + q31;

  // Q fragments (B-operand of 32x32x16): B[k=d][col=q], k = ks*16 + h2*8 + e
  bf16x8 qf[4];
  #pragma unroll
  for (int ks = 0; ks < 4; ++ks)
    qf[ks] = *(const bf16x8*)(Qh + ((size_t)hh * T_TOK + qw) * HD + ks * 16 + h2 * 8);

  f32x16 acc_o[2] = {};
  float m = -INFINITY, l = 0.f;

  // staging (identical to R6): each wave stages 16 rows of K tile and V tile
  const int ldrow = lane >> 3;
  const int colS  = ((lane & 7) * 16) ^ (ldrow << 4);
  const unsigned short* kga = Kh + ((size_t)hh * T_TOK + wv * 16 + ldrow) * HD + (colS >> 1);
  const unsigned short* vga = Vt + ((size_t)hh * HD + wv * 16 + ldrow) * T_TOK + (colS >> 1);
  char* ksd = (char*)&Ks[0][0] + wv * 2048;
  char* vsd = (char*)&Vs[0][0] + wv * 2048;
  const float* mrow = mask + (size_t)qw * T_TOK;
  const int hasmask = flags[z * NQB + qx];

  auto stage = [&](int buf, int s0) {
    __builtin_amdgcn_global_load_lds(
        (const __attribute__((address_space(1))) unsigned int*)(kga + (size_t)s0 * HD),
        (__attribute__((address_space(3))) unsigned int*)(ksd + buf * 8192), 16, 0, 0);
    __builtin_amdgcn_global_load_lds(
        (const __attribute__((address_space(1))) unsigned int*)(kga + (size_t)s0 * HD + 8 * HD),
        (__attribute__((address_space(3))) unsigned int*)(ksd + buf * 8192 + 1024), 16, 0, 0);
    __builtin_amdgcn_global_load_lds(
        (const __attribute__((address_space(1))) unsigned int*)(vga + s0),
        (__attribute__((address_space(3))) unsigned int*)(vsd + buf * 8192), 16, 0, 0);
    __builtin_amdgcn_global_load_lds(
        (const __attribute__((address_space(1))) unsigned int*)(vga + s0 + 8 * T_TOK),
        (__attribute__((address_space(3))) unsigned int*)(vsd + buf * 8192 + 1024), 16, 0, 0);
  };

  float4 mk[8];  // mask tile: mk[kvb*4+g] = mask[qw][s0 + kvb*32 + g*8 + 4*h2 ..+3]

  auto tilecomp = [&](int cur, bool usemask) {
    // QK^T: S^T[kv, q] = K[kv,:] x Q^T; A-frag row=kv=q31(+32*kvb), k=h2*8+e
    f32x16 as0 = {}, as1 = {};
    __builtin_amdgcn_s_setprio(1);
    #pragma unroll
    for (int ks = 0; ks < 4; ++ks) {
      bf16x8 kf0 = *(const bf16x8*)&Ks[cur][swz(q31,      ks * 32 + h2 * 16)];
      bf16x8 kf1 = *(const bf16x8*)&Ks[cur][swz(32 + q31, ks * 32 + h2 * 16)];
      as0 = __builtin_amdgcn_mfma_f32_32x32x16_bf16(kf0, qf[ks], as0, 0, 0, 0);
      as1 = __builtin_amdgcn_mfma_f32_32x32x16_bf16(kf1, qf[ks], as1, 0, 0, 0);
    }
    __builtin_amdgcn_s_setprio(0);

    // sv[kvb][reg]: S + mask; C-layout: col=q31, row(kv_local)=(reg&3)+8*(reg>>2)+4*h2
    float sv[2][16];
    #pragma unroll
    for (int reg = 0; reg < 16; ++reg) {
      float a0 = as0[reg], a1 = as1[reg];
      if (usemask) {
        float m0v = (&mk[0 + (reg >> 2)].x)[reg & 3];
        float m1v = (&mk[4 + (reg >> 2)].x)[reg & 3];
        a0 = fmaf(m0v, LOG2E, a0);
        a1 = fmaf(m1v, LOG2E, a1);
      }
      sv[0][reg] = a0;
      sv[1][reg] = a1;
    }

    // row max: local tree over 32 (compiler fuses to max3) + one cross-half swap
    float p0 = sv[0][0];
    #pragma unroll
    for (int i = 1; i < 16; ++i) p0 = fmaxf(p0, sv[0][i]);
    #pragma unroll
    for (int i = 0; i < 16; ++i) p0 = fmaxf(p0, sv[1][i]);
    float pmax = fmaxf(p0, __shfl_xor(p0, 32));

    // defer-max: rescale only when running max grew > 8 (log2 units); sc lane-local
    if (__any(pmax > m + 8.f)) {
      float mnew = fmaxf(m, pmax);
      float sc = __builtin_amdgcn_exp2f(m - mnew);
      m = mnew;
      l *= sc;
      #pragma unroll
      for (int db = 0; db < 2; ++db)
        #pragma unroll
        for (int i = 0; i < 16; ++i) acc_o[db][i] *= sc;
    }

    // P = exp2(sv - m); pack to u32 pairs; l accumulates per-lane (no shuffle)
    float ps = 0.f;
    unsigned int pk[16];  // pk[kvb*8 + j*2 + w], group j = reg>>2
    #pragma unroll
    for (int kvb = 0; kvb < 2; ++kvb)
      #pragma unroll
      for (int j = 0; j < 4; ++j) {
        float e0 = __builtin_amdgcn_exp2f(sv[kvb][j * 4 + 0] - m);
        float e1 = __builtin_amdgcn_exp2f(sv[kvb][j * 4 + 1] - m);
        float e2 = __builtin_amdgcn_exp2f(sv[kvb][j * 4 + 2] - m);
        float e3 = __builtin_amdgcn_exp2f(sv[kvb][j * 4 + 3] - m);
        ps += (e0 + e1) + (e2 + e3);
        pk[kvb * 8 + j * 2 + 0] = (unsigned int)f2bf(e0) | ((unsigned int)f2bf(e1) << 16);
        pk[kvb * 8 + j * 2 + 1] = (unsigned int)f2bf(e2) | ((unsigned int)f2bf(e3) << 16);
      }
    l += ps;

    // PV: O^T[d,q] += V^T[d,kv] x P[kv,q].
    // B-frag(kstep s) needs group j*=2s+h2 full 8 offsets; own half + partner half
    // via shfl_xor(32): send own pk of group (2s+1-h2), receive partner's (2s+h2).
    #pragma unroll
    for (int kvb = 0; kvb < 2; ++kvb)
      #pragma unroll
      for (int s = 0; s < 2; ++s) {
        unsigned int A0 = pk[kvb * 8 + (2 * s) * 2 + 0];
        unsigned int A1 = pk[kvb * 8 + (2 * s) * 2 + 1];
        unsigned int B0 = pk[kvb * 8 + (2 * s + 1) * 2 + 0];
        unsigned int B1 = pk[kvb * 8 + (2 * s + 1) * 2 + 1];
        unsigned int s0w = h2 ? A0 : B0;
        unsigned int s1w = h2 ? A1 : B1;
        unsigned int R0 = (unsigned int)__shfl_xor((int)s0w, 32);
        unsigned int R1 = (unsigned int)__shfl_xor((int)s1w, 32);
        u32x4 fr;
        fr[0] = h2 ? R0 : A0;
        fr[1] = h2 ? R1 : A1;
        fr[2] = h2 ? B0 : R0;
        fr[3] = h2 ? B1 : R1;
        bf16x8 pfrag = __builtin_bit_cast(bf16x8, fr);
        __builtin_amdgcn_s_setprio(1);
        #pragma unroll
        for (int db = 0; db < 2; ++db) {
          bf16x8 vf = *(const bf16x8*)&Vs[cur][swz(db * 32 + q31, kvb * 64 + s * 32 + h2 * 16)];
          acc_o[db] = __builtin_amdgcn_mfma_f32_32x32x16_bf16(vf, pfrag, acc_o[db], 0, 0, 0);
        }
        __builtin_amdgcn_s_setprio(0);
      }
  };

  stage(0, kv0);  // prologue

  if (hasmask) {
    for (int it = 0; it < NT - 1; ++it) {
      const int s0 = kv0 + it * 64;
      #pragma unroll
      for (int kvb = 0; kvb < 2; ++kvb)
        #pragma unroll
        for (int g = 0; g < 4; ++g)
          mk[kvb * 4 + g] = *(const float4*)(mrow + s0 + kvb * 32 + g * 8 + 4 * h2);
      stage((it + 1) & 1, s0 + 64);
      VMCNT(12);           // wait current tile's 4 stage loads (mask auto-waited at use)
      SB();
      __builtin_amdgcn_s_barrier();
      SB();
      tilecomp(it & 1, true);
      __builtin_amdgcn_s_barrier();
    }
    const int s0 = kv0 + (NT - 1) * 64;
    #pragma unroll
    for (int kvb = 0; kvb < 2; ++kvb)
      #pragma unroll
      for (int g = 0; g < 4; ++g)
        mk[kvb * 4 + g] = *(const float4*)(mrow + s0 + kvb * 32 + g * 8 + 4 * h2);
    VMCNT(8);
    SB();
    __builtin_amdgcn_s_barrier();
    SB();
    tilecomp((NT - 1) & 1, true);
  } else {
    for (int it = 0; it < NT - 1; ++it) {
      const int s0 = kv0 + it * 64;
      stage((it + 1) & 1, s0 + 64);
      VMCNT(4);            // wait current tile's 4 stage loads only
      SB();
      __builtin_amdgcn_s_barrier();
      SB();
      tilecomp(it & 1, false);
      __builtin_amdgcn_s_barrier();
    }
    VMCNT(0);
    SB();
    __builtin_amdgcn_s_barrier();
    SB();
    tilecomp((NT - 1) & 1, false);
  }

  // epilogue: O^T[d][q] regs -> Op rows (q fixed per lane; 4 contiguous d per store)
  float lf = l + __shfl_xor(l, 32);
  float* oprow = Op + (((size_t)z * T_TOK + qw) * NH + hh) * HD;
  #pragma unroll
  for (int db = 0; db < 2; ++db)
    #pragma unroll
    for (int g = 0; g < 4; ++g) {
      float4 o4;
      o4.x = acc_o[db][g * 4 + 0];
      o4.y = acc_o[db][g * 4 + 1];
      o4.z = acc_o[db][g * 4 + 2];
      o4.w = acc_o[db][g * 4 + 3];
      *(float4*)(oprow + db * 32 + g * 8 + 4 * h2) = o4;
    }
  if (h2 == 0) {
    size_t mi = ((size_t)z * T_TOK + qw) * NH + hh;
    Mp[mi] = m;
    Lp[mi] = lf;
  }
}

// ---------------- combine KV-split partials (log2-domain maxes) ----------------
__global__ __launch_bounds__(256) void combine(const float* __restrict__ Op,
                                               const float* __restrict__ Mp,
                                               const float* __restrict__ Lp,
                                               unsigned short* __restrict__ Ob) {
  int idx = blockIdx.x * 256 + threadIdx.x;  // T*256 total (4 floats each)
  int t = idx >> 8;
  int q4 = (idx & 255) * 4;  // within [HID): h*64 + d
  int h = q4 >> 6, d = q4 & 63;
  float mz[KVSPLIT], lz[KVSPLIT];
  float ms = -INFINITY;
  #pragma unroll
  for (int zz = 0; zz < KVSPLIT; ++zz) {
    size_t mi = ((size_t)zz * T_TOK + t) * NH + h;
    mz[zz] = Mp[mi];
    lz[zz] = Lp[mi];
    ms = fmaxf(ms, mz[zz]);
  }
  float lsum = 0.f;
  float w[KVSPLIT];
  #pragma unroll
  for (int zz = 0; zz < KVSPLIT; ++zz) {
    w[zz] = __builtin_amdgcn_exp2f(mz[zz] - ms);
    lsum += lz[zz] * w[zz];
  }
  float4 o = {0.f, 0.f, 0.f, 0.f};
  #pragma unroll
  for (int zz = 0; zz < KVSPLIT; ++zz) {
    float4 p = *(const float4*)(Op + (((size_t)zz * T_TOK + t) * NH + h) * HD + d);
    o.x += p.x * w[zz]; o.y += p.y * w[zz];
    o.z += p.z * w[zz]; o.w += p.w * w[zz];
  }
  float inv = 1.f / lsum;
  ushort4 ob;
  ob.x = f2bf(o.x * inv); ob.y = f2bf(o.y * inv);
  ob.z = f2bf(o.z * inv); ob.w = f2bf(o.w * inv);
  *(ushort4*)(Ob + (size_t)t * HID + q4) = ob;
}

extern "C" void kernel_launch(void* const* d_in, const int* in_sizes, int n_in,
                              void* d_out, int out_size, void* d_ws, size_t ws_size,
                              hipStream_t stream) {
  const float* X    = (const float*)d_in[0];
  const float* Wqkv = (const float*)d_in[1];
  const float* Wo   = (const float*)d_in[2];
  const float* mask = (const float*)d_in[3];
  const int*   pos  = (const int*)d_in[4];
  float* out = (float*)d_out;

  char* ws = (char*)d_ws;
  size_t off = 0;
  auto alloc = [&](size_t bytes) {
    char* p = ws + off;
    off += (bytes + 255) & ~(size_t)255;
    return p;
  };
  unsigned short* Xb    = (unsigned short*)alloc((size_t)T_TOK * HID * 2);
  unsigned short* WqkvT = (unsigned short*)alloc((size_t)3 * HID * HID * 2);
  unsigned short* WoT   = (unsigned short*)alloc((size_t)HID * HID * 2);
  unsigned short* Qh    = (unsigned short*)alloc((size_t)NH * T_TOK * HD * 2);
  unsigned short* Kh    = (unsigned short*)alloc((size_t)NH * T_TOK * HD * 2);
  unsigned short* Vt    = (unsigned short*)alloc((size_t)NH * HD * T_TOK * 2);
  unsigned short* Ob    = (unsigned short*)alloc((size_t)T_TOK * HID * 2);
  float*          ctab  = (float*)alloc((size_t)T_TOK * 32 * 4);
  float*          stab  = (float*)alloc((size_t)T_TOK * 32 * 4);
  float*          Mp    = (float*)alloc((size_t)KVSPLIT * T_TOK * NH * 4);
  float*          Lp    = (float*)alloc((size_t)KVSPLIT * T_TOK * NH * 4);
  int*            flags = (int*)alloc((size_t)KVSPLIT * NQB * 4);
  // REGION: QKV (f32 T x 3H = 37.75MB) aliased with Opart (KVSPLIT x T x HID f32 = 50.3MB).
  // QKV is dead once rope_split + v_transpose complete, before flash_attn writes Op.
  float*          QKV   = (float*)alloc((size_t)KVSPLIT * T_TOK * HID * 4);
  float*          Op    = QKV;

  cvt_bf16<<<(T_TOK * HID / 4 + 255) / 256, 256, 0, stream>>>(X, Xb, T_TOK * HID);
  transpose_cvt<<<dim3(3 * HID / 32, HID / 32), 256, 0, stream>>>(Wqkv, WqkvT, HID, 3 * HID);
  transpose_cvt<<<dim3(HID / 32, HID / 32), 256, 0, stream>>>(Wo, WoT, HID, HID);
  rope_table<<<T_TOK * 32 / 256, 256, 0, stream>>>(pos, ctab, stab);
  mask_flags<<<dim3(NQB, KVSPLIT), 1024, 0, stream>>>(mask, flags);

  gemm_bt<<<dim3(3 * HID / 128, T_TOK / 128), 256, 0, stream>>>(Xb, WqkvT, QKV, T_TOK, 3 * HID, HID);

  rope_split<<<T_TOK * NH * 32 / 256, 256, 0, stream>>>(QKV, ctab, stab, Qh, Kh);
  v_transpose<<<dim3(T_TOK / 64, NH), 256, 0, stream>>>(QKV, Vt);

  flash_attn<<<dim3(NQB * NH * KVSPLIT), 256, 0, stream>>>(Qh, Kh, Vt, mask, flags, Op, Mp, Lp);
  combine<<<T_TOK, 256, 0, stream>>>(Op, Mp, Lp, Ob);

  gemm_bt<<<dim3(HID / 128, T_TOK / 128), 256, 0, stream>>>(Ob, WoT, out, T_TOK, HID, HID);
}

// Round 9
// 190.383 us; speedup vs baseline: 1.4964x; 1.0040x over previous
//
#include <hip/hip_runtime.h>
#include <hip/hip_bf16.h>
#include <math.h>

#define T_TOK 3072
#define HID   1024
#define NH    16
#define HD    64
#define KVSPLIT 2
#define KVCHUNK (T_TOK / KVSPLIT)   // 1536
#define NQB (T_TOK / 128)           // 24 q-tiles of 128 rows
#define LOG2E 1.4426950408889634f

typedef __attribute__((ext_vector_type(8))) short bf16x8;
typedef __attribute__((ext_vector_type(8))) unsigned short u16x8;
typedef __attribute__((ext_vector_type(4))) float f32x4;
typedef __attribute__((ext_vector_type(16))) float f32x16;
typedef __attribute__((ext_vector_type(4))) unsigned int u32x4;

#define VMCNT(n) asm volatile("s_waitcnt vmcnt(" #n ")" ::: "memory")
#define SB() __builtin_amdgcn_sched_barrier(0)

static __device__ __forceinline__ unsigned short f2bf(float x) {
  __hip_bfloat16 h = __float2bfloat16(x);
  return __builtin_bit_cast(unsigned short, h);
}
static __device__ __forceinline__ float bf2f(unsigned short u) {
  unsigned int v = (unsigned int)u << 16;
  return __builtin_bit_cast(float, v);
}

// swizzled LDS short-index for a [rows][64 bf16] tile, row stride 128B.
static __device__ __forceinline__ int swz(int row, int cb) {
  return row * 64 + ((cb ^ ((row & 7) << 4)) >> 1);
}

// ---------------- elementwise fp32 -> bf16 ----------------
__global__ __launch_bounds__(256) void cvt_bf16(const float* __restrict__ in,
                                                unsigned short* __restrict__ out, int n) {
  int i = (blockIdx.x * 256 + threadIdx.x) * 4;
  if (i < n) {
    float4 v = *(const float4*)(in + i);
    ushort4 o;
    o.x = f2bf(v.x); o.y = f2bf(v.y); o.z = f2bf(v.z); o.w = f2bf(v.w);
    *(ushort4*)(out + i) = o;
  }
}

// ---------------- transpose + convert: out[C][R] = bf16(in[R][C]) ----------------
__global__ __launch_bounds__(256) void transpose_cvt(const float* __restrict__ in,
                                                     unsigned short* __restrict__ out,
                                                     int R, int C) {
  __shared__ float tile[32][33];
  int c0 = blockIdx.x * 32, r0 = blockIdx.y * 32;
  int tx = threadIdx.x & 31, ty = threadIdx.x >> 5; // ty 0..7
  #pragma unroll
  for (int i = 0; i < 32; i += 8)
    tile[ty + i][tx] = in[(size_t)(r0 + ty + i) * C + c0 + tx];
  __syncthreads();
  #pragma unroll
  for (int i = 0; i < 32; i += 8)
    out[(size_t)(c0 + ty + i) * R + r0 + tx] = f2bf(tile[tx][ty + i]);
}

// ---------------- RoPE cos/sin tables [T][32] ----------------
__global__ __launch_bounds__(256) void rope_table(const int* __restrict__ pos,
                                                  float* __restrict__ ctab,
                                                  float* __restrict__ stab) {
  int i = blockIdx.x * 256 + threadIdx.x;  // T*32
  int t = i >> 5, j = i & 31;
  float inv = expf(-(float)j * 0.28782313662425572f);  // 10000^(-j/32)
  float f = (float)pos[t] * inv;
  ctab[i] = cosf(f);
  stab[i] = sinf(f);
}

// ---------------- fused RoPE split + V transpose (reads bf16 QKV once) ----------------
// grid (T/64, NH), block 256: thread = (t_local = tid>>2)*4 + (g = tid&3).
// Handles Q,K rope (j = g*8..+7 paired with j+32) and V transpose via LDS.
// Q pre-scaled by 0.125*log2e (exp2-domain softmax).
__global__ __launch_bounds__(256) void rope_v(const unsigned short* __restrict__ QKVb,
                                              const float* __restrict__ ctab,
                                              const float* __restrict__ stab,
                                              unsigned short* __restrict__ Qh,
                                              unsigned short* __restrict__ Kh,
                                              unsigned short* __restrict__ Vt) {
  const float QSCL = 0.18033688011112042f;  // 0.125 * log2e
  const int h = blockIdx.y;
  const int t0 = blockIdx.x * 64;
  const int g = threadIdx.x & 3, tl = threadIdx.x >> 2;
  const int t = t0 + tl;
  __shared__ unsigned short vlds[64][72];

  const size_t rowb = (size_t)t * (3 * HID) + h * HD + g * 8;
  u16x8 qa = *(const u16x8*)(QKVb + rowb);
  u16x8 qb = *(const u16x8*)(QKVb + rowb + 32);
  u16x8 ka = *(const u16x8*)(QKVb + rowb + HID);
  u16x8 kb = *(const u16x8*)(QKVb + rowb + HID + 32);
  u16x8 va = *(const u16x8*)(QKVb + rowb + 2 * HID);
  u16x8 vb = *(const u16x8*)(QKVb + rowb + 2 * HID + 32);

  u16x8 qo0, qo1, ko0, ko1;
  #pragma unroll
  for (int e = 0; e < 8; ++e) {
    int j = g * 8 + e;
    float c = ctab[t * 32 + j], s = stab[t * 32 + j];
    float q1 = bf2f(qa[e]), q2 = bf2f(qb[e]);
    float k1 = bf2f(ka[e]), k2 = bf2f(kb[e]);
    qo0[e] = f2bf((q1 * c - q2 * s) * QSCL);
    qo1[e] = f2bf((q2 * c + q1 * s) * QSCL);
    ko0[e] = f2bf(k1 * c - k2 * s);
    ko1[e] = f2bf(k2 * c + k1 * s);
    vlds[tl][j] = va[e];
    vlds[tl][32 + j] = vb[e];
  }
  size_t ob = ((size_t)h * T_TOK + t) * HD + g * 8;
  *(u16x8*)(Qh + ob) = qo0;
  *(u16x8*)(Qh + ob + 32) = qo1;
  *(u16x8*)(Kh + ob) = ko0;
  *(u16x8*)(Kh + ob + 32) = ko1;

  __syncthreads();
  // transposed V write: d = tl, t-range = t0 + g*16 .. +15
  u16x8 o0, o1;
  #pragma unroll
  for (int e = 0; e < 8; ++e) {
    o0[e] = vlds[g * 16 + e][tl];
    o1[e] = vlds[g * 16 + 8 + e][tl];
  }
  size_t vb2 = ((size_t)h * HD + tl) * T_TOK + t0 + g * 16;
  *(u16x8*)(Vt + vb2) = o0;
  *(u16x8*)(Vt + vb2 + 8) = o1;
}

// ---------------- per-(q-tile128, kv-chunk) mask nonzero flags ----------------
__global__ __launch_bounds__(1024) void mask_flags(const float* __restrict__ mask,
                                                   int* __restrict__ flags) {
  int qx = blockIdx.x, z = blockIdx.y;
  const float* base = mask + (size_t)(qx * 128) * T_TOK + z * KVCHUNK;
  int any = 0;
  const int NC4 = KVCHUNK / 4;  // 384
  for (int i = threadIdx.x; i < 128 * NC4; i += 1024) {
    int row = i / NC4, c = i - row * NC4;
    float4 v = *(const float4*)(base + (size_t)row * T_TOK + c * 4);
    any |= (v.x != 0.f) | (v.y != 0.f) | (v.z != 0.f) | (v.w != 0.f);
  }
  __shared__ int s;
  if (threadIdx.x == 0) s = 0;
  __syncthreads();
  if (__any(any) && (threadIdx.x & 63) == 0) s = 1;  // benign same-value race
  __syncthreads();
  if (threadIdx.x == 0) flags[z * NQB + qx] = s;
}

// ---------------- GEMM core: 128x128 tile, BK=64, epilogue templated ----------------
template <int OBF16>
__device__ __forceinline__ void gemm_body(const unsigned short* __restrict__ A,
                                          const unsigned short* __restrict__ Bt,
                                          float* __restrict__ C,
                                          unsigned short* __restrict__ Cb,
                                          int M, int N, int K) {
  __shared__ unsigned short As[128 * 64];
  __shared__ unsigned short Bs[128 * 64];
  const int lane = threadIdx.x & 63;
  const int wv = threadIdx.x >> 6;
  const int wm = wv >> 1, wn = wv & 1;
  const int r = lane & 15, hi = lane >> 4;
  const int m0 = blockIdx.y * 128, n0 = blockIdx.x * 128;
  f32x4 acc[4][4] = {};
  for (int kt = 0; kt < K; kt += 64) {
    __syncthreads();
    #pragma unroll
    for (int i = 0; i < 4; ++i) {
      int o = (wv * 4 + i) * 1024 + lane * 16;  // byte offset into 16KB tile
      int row = o >> 7;                          // 128B per row (64 bf16)
      int col = (o & 127) >> 1;
      const unsigned short* ga = A + (size_t)(m0 + row) * K + kt + col;
      __builtin_amdgcn_global_load_lds(
          (const __attribute__((address_space(1))) unsigned int*)ga,
          (__attribute__((address_space(3))) unsigned int*)((char*)As + (wv * 4 + i) * 1024),
          16, 0, 0);
      const unsigned short* gb = Bt + (size_t)(n0 + row) * K + kt + col;
      __builtin_amdgcn_global_load_lds(
          (const __attribute__((address_space(1))) unsigned int*)gb,
          (__attribute__((address_space(3))) unsigned int*)((char*)Bs + (wv * 4 + i) * 1024),
          16, 0, 0);
    }
    __syncthreads();
    #pragma unroll
    for (int kk = 0; kk < 2; ++kk) {
      bf16x8 a[4], b[4];
      #pragma unroll
      for (int tm = 0; tm < 4; ++tm)
        a[tm] = *(const bf16x8*)&As[(wm * 64 + tm * 16 + r) * 64 + kk * 32 + hi * 8];
      #pragma unroll
      for (int tn = 0; tn < 4; ++tn)
        b[tn] = *(const bf16x8*)&Bs[(wn * 64 + tn * 16 + r) * 64 + kk * 32 + hi * 8];
      #pragma unroll
      for (int tm = 0; tm < 4; ++tm)
        #pragma unroll
        for (int tn = 0; tn < 4; ++tn)
          acc[tm][tn] = __builtin_amdgcn_mfma_f32_16x16x32_bf16(a[tm], b[tn], acc[tm][tn], 0, 0, 0);
    }
  }
  #pragma unroll
  for (int tm = 0; tm < 4; ++tm)
    #pragma unroll
    for (int tn = 0; tn < 4; ++tn) {
      int colg = n0 + wn * 64 + tn * 16 + r;
      int rowg = m0 + wm * 64 + tm * 16 + hi * 4;
      if (OBF16) {
        unsigned short* cp = Cb + (size_t)rowg * N + colg;
        #pragma unroll
        for (int j = 0; j < 4; ++j) cp[(size_t)j * N] = f2bf(acc[tm][tn][j]);
      } else {
        float* cp = C + (size_t)rowg * N + colg;
        #pragma unroll
        for (int j = 0; j < 4; ++j) cp[(size_t)j * N] = acc[tm][tn][j];
      }
    }
}

__global__ __launch_bounds__(256) void gemm_bt(const unsigned short* __restrict__ A,
                                               const unsigned short* __restrict__ Bt,
                                               float* __restrict__ C, int M, int N, int K) {
  gemm_body<0>(A, Bt, C, nullptr, M, N, K);
}
__global__ __launch_bounds__(256) void gemm_bt_bf16(const unsigned short* __restrict__ A,
                                                    const unsigned short* __restrict__ Bt,
                                                    unsigned short* __restrict__ Cb,
                                                    int M, int N, int K) {
  gemm_body<1>(A, Bt, nullptr, Cb, M, N, K);
}

// ---------------- flash attention: 32x32 MFMA, shuffle-free PV ----------------
// grid 1D NQB*NH*KVSPLIT, XCD-remapped. block 256 = 4 waves x 32 q-rows = 128 q.
// Swapped QK^T (S^T col=lane&31=q): softmax = local tree + ONE shfl_xor(32);
// rescale lane-local; l per-lane partial.
// PV k-slot permutation sigma(s,h2,e) = s*16 + (e>>2)*8 + h2*4 + (e&3) makes each
// lane's OWN pk words the exact B-fragment (no shuffles); V read as 2x ds_read_b64.
// Counted-vmcnt double-buffer pipeline (R6-proven).
__global__ __launch_bounds__(256) void flash_attn(const unsigned short* __restrict__ Qh,
                                                  const unsigned short* __restrict__ Kh,
                                                  const unsigned short* __restrict__ Vt,
                                                  const float* __restrict__ mask,
                                                  const int* __restrict__ flags,
                                                  float* __restrict__ Op,
                                                  float* __restrict__ Mp,
                                                  float* __restrict__ Lp) {
  const int NBLK = NQB * NH * KVSPLIT;              // 768, divisible by 8
  int id = blockIdx.x;
  int sid = (id & 7) * (NBLK / 8) + (id >> 3);      // bijective XCD chunking
  const int hh = sid & 15;
  int t2 = sid >> 4;
  const int qx = t2 % NQB;
  const int z  = t2 / NQB;
  const int q0 = qx * 128;
  const int kv0 = z * KVCHUNK;
  const int NT = KVCHUNK / 64;                      // 24

  __shared__ unsigned short Ks[2][64 * 64];
  __shared__ unsigned short Vs[2][64 * 64];
  const int lane = threadIdx.x & 63, wv = threadIdx.x >> 6;
  const int q31 = lane & 31, h2 = lane >> 5;
  const int qw = q0 + wv * 32 + q31;

  // Q fragments (B-operand of 32x32x16): B[k=d][col=q], k = ks*16 + h2*8 + e
  bf16x8 qf[4];
  #pragma unroll
  for (int ks = 0; ks < 4; ++ks)
    qf[ks] = *(const bf16x8*)(Qh + ((size_t)hh * T_TOK + qw) * HD + ks * 16 + h2 * 8);

  f32x16 acc_o[2] = {};
  float m = -INFINITY, l = 0.f;

  const int ldrow = lane >> 3;
  const int colS  = ((lane & 7) * 16) ^ (ldrow << 4);
  const unsigned short* kga = Kh + ((size_t)hh * T_TOK + wv * 16 + ldrow) * HD + (colS >> 1);
  const unsigned short* vga = Vt + ((size_t)hh * HD + wv * 16 + ldrow) * T_TOK + (colS >> 1);
  char* ksd = (char*)&Ks[0][0] + wv * 2048;
  char* vsd = (char*)&Vs[0][0] + wv * 2048;
  const float* mrow = mask + (size_t)qw * T_TOK;
  const int hasmask = flags[z * NQB + qx];

  auto stage = [&](int buf, int s0) {
    __builtin_amdgcn_global_load_lds(
        (const __attribute__((address_space(1))) unsigned int*)(kga + (size_t)s0 * HD),
        (__attribute__((address_space(3))) unsigned int*)(ksd + buf * 8192), 16, 0, 0);
    __builtin_amdgcn_global_load_lds(
        (const __attribute__((address_space(1))) unsigned int*)(kga + (size_t)s0 * HD + 8 * HD),
        (__attribute__((address_space(3))) unsigned int*)(ksd + buf * 8192 + 1024), 16, 0, 0);
    __builtin_amdgcn_global_load_lds(
        (const __attribute__((address_space(1))) unsigned int*)(vga + s0),
        (__attribute__((address_space(3))) unsigned int*)(vsd + buf * 8192), 16, 0, 0);
    __builtin_amdgcn_global_load_lds(
        (const __attribute__((address_space(1))) unsigned int*)(vga + s0 + 8 * T_TOK),
        (__attribute__((address_space(3))) unsigned int*)(vsd + buf * 8192 + 1024), 16, 0, 0);
  };

  float4 mk[8];  // mk[kvb*4+g] = mask[qw][s0 + kvb*32 + g*8 + 4*h2 ..+3]

  auto tilecomp = [&](int cur, bool usemask) {
    // QK^T: S^T[kv, q]; A-frag row=kv=q31(+32*kvb), k=h2*8+e
    f32x16 as0 = {}, as1 = {};
    __builtin_amdgcn_s_setprio(1);
    #pragma unroll
    for (int ks = 0; ks < 4; ++ks) {
      bf16x8 kf0 = *(const bf16x8*)&Ks[cur][swz(q31,      ks * 32 + h2 * 16)];
      bf16x8 kf1 = *(const bf16x8*)&Ks[cur][swz(32 + q31, ks * 32 + h2 * 16)];
      as0 = __builtin_amdgcn_mfma_f32_32x32x16_bf16(kf0, qf[ks], as0, 0, 0, 0);
      as1 = __builtin_amdgcn_mfma_f32_32x32x16_bf16(kf1, qf[ks], as1, 0, 0, 0);
    }
    __builtin_amdgcn_s_setprio(0);

    // sv[kvb][reg]: C-layout col=q31, row(kv_local)=(reg&3)+8*(reg>>2)+4*h2
    float sv[2][16];
    #pragma unroll
    for (int reg = 0; reg < 16; ++reg) {
      float a0 = as0[reg], a1 = as1[reg];
      if (usemask) {
        float m0v = (&mk[0 + (reg >> 2)].x)[reg & 3];
        float m1v = (&mk[4 + (reg >> 2)].x)[reg & 3];
        a0 = fmaf(m0v, LOG2E, a0);
        a1 = fmaf(m1v, LOG2E, a1);
      }
      sv[0][reg] = a0;
      sv[1][reg] = a1;
    }

    // row max: local tree + one cross-half swap
    float p0 = sv[0][0];
    #pragma unroll
    for (int i = 1; i < 16; ++i) p0 = fmaxf(p0, sv[0][i]);
    #pragma unroll
    for (int i = 0; i < 16; ++i) p0 = fmaxf(p0, sv[1][i]);
    float pmax = fmaxf(p0, __shfl_xor(p0, 32));

    // defer-max: rescale only when running max grew > 8 (log2 units)
    if (__any(pmax > m + 8.f)) {
      float mnew = fmaxf(m, pmax);
      float sc = __builtin_amdgcn_exp2f(m - mnew);
      m = mnew;
      l *= sc;
      #pragma unroll
      for (int db = 0; db < 2; ++db)
        #pragma unroll
        for (int i = 0; i < 16; ++i) acc_o[db][i] *= sc;
    }

    // P = exp2(sv - m); pack; l per-lane
    float ps = 0.f;
    unsigned int pk[16];  // pk[kvb*8 + j*2 + w]: group j rows 8j+4h2+{0..3}
    #pragma unroll
    for (int kvb = 0; kvb < 2; ++kvb)
      #pragma unroll
      for (int j = 0; j < 4; ++j) {
        float e0 = __builtin_amdgcn_exp2f(sv[kvb][j * 4 + 0] - m);
        float e1 = __builtin_amdgcn_exp2f(sv[kvb][j * 4 + 1] - m);
        float e2 = __builtin_amdgcn_exp2f(sv[kvb][j * 4 + 2] - m);
        float e3 = __builtin_amdgcn_exp2f(sv[kvb][j * 4 + 3] - m);
        ps += (e0 + e1) + (e2 + e3);
        pk[kvb * 8 + j * 2 + 0] = (unsigned int)f2bf(e0) | ((unsigned int)f2bf(e1) << 16);
        pk[kvb * 8 + j * 2 + 1] = (unsigned int)f2bf(e2) | ((unsigned int)f2bf(e3) << 16);
      }
    l += ps;

    // PV (shuffle-free): k-slot sigma gives pfrag = pk[kvb*8 + 4s .. +3] directly;
    // vf = V^T cols {base0..+3, base0+8..+11}, base0 = kvb*32 + s*16 + h2*4.
    __builtin_amdgcn_s_setprio(1);
    #pragma unroll
    for (int kvb = 0; kvb < 2; ++kvb)
      #pragma unroll
      for (int s = 0; s < 2; ++s) {
        u32x4 fr;
        fr[0] = pk[kvb * 8 + 4 * s + 0];
        fr[1] = pk[kvb * 8 + 4 * s + 1];
        fr[2] = pk[kvb * 8 + 4 * s + 2];
        fr[3] = pk[kvb * 8 + 4 * s + 3];
        bf16x8 pfrag = __builtin_bit_cast(bf16x8, fr);
        const int cb0 = kvb * 64 + s * 32 + h2 * 8;  // byte col of 4-elem run
        #pragma unroll
        for (int db = 0; db < 2; ++db) {
          const int row = db * 32 + q31;
          uint2 v0 = *(const uint2*)&Vs[cur][swz(row, cb0)];
          uint2 v1 = *(const uint2*)&Vs[cur][swz(row, cb0 + 16)];
          u32x4 vv; vv[0] = v0.x; vv[1] = v0.y; vv[2] = v1.x; vv[3] = v1.y;
          bf16x8 vf = __builtin_bit_cast(bf16x8, vv);
          acc_o[db] = __builtin_amdgcn_mfma_f32_32x32x16_bf16(vf, pfrag, acc_o[db], 0, 0, 0);
        }
      }
    __builtin_amdgcn_s_setprio(0);
  };

  stage(0, kv0);  // prologue

  if (hasmask) {
    for (int it = 0; it < NT - 1; ++it) {
      const int s0 = kv0 + it * 64;
      #pragma unroll
      for (int kvb = 0; kvb < 2; ++kvb)
        #pragma unroll
        for (int g = 0; g < 4; ++g)
          mk[kvb * 4 + g] = *(const float4*)(mrow + s0 + kvb * 32 + g * 8 + 4 * h2);
      stage((it + 1) & 1, s0 + 64);
      VMCNT(12);
      SB();
      __builtin_amdgcn_s_barrier();
      SB();
      tilecomp(it & 1, true);
      __builtin_amdgcn_s_barrier();
    }
    const int s0 = kv0 + (NT - 1) * 64;
    #pragma unroll
    for (int kvb = 0; kvb < 2; ++kvb)
      #pragma unroll
      for (int g = 0; g < 4; ++g)
        mk[kvb * 4 + g] = *(const float4*)(mrow + s0 + kvb * 32 + g * 8 + 4 * h2);
    VMCNT(8);
    SB();
    __builtin_amdgcn_s_barrier();
    SB();
    tilecomp((NT - 1) & 1, true);
  } else {
    for (int it = 0; it < NT - 1; ++it) {
      const int s0 = kv0 + it * 64;
      stage((it + 1) & 1, s0 + 64);
      VMCNT(4);
      SB();
      __builtin_amdgcn_s_barrier();
      SB();
      tilecomp(it & 1, false);
      __builtin_amdgcn_s_barrier();
    }
    VMCNT(0);
    SB();
    __builtin_amdgcn_s_barrier();
    SB();
    tilecomp((NT - 1) & 1, false);
  }

  // epilogue
  float lf = l + __shfl_xor(l, 32);
  float* oprow = Op + (((size_t)z * T_TOK + qw) * NH + hh) * HD;
  #pragma unroll
  for (int db = 0; db < 2; ++db)
    #pragma unroll
    for (int g = 0; g < 4; ++g) {
      float4 o4;
      o4.x = acc_o[db][g * 4 + 0];
      o4.y = acc_o[db][g * 4 + 1];
      o4.z = acc_o[db][g * 4 + 2];
      o4.w = acc_o[db][g * 4 + 3];
      *(float4*)(oprow + db * 32 + g * 8 + 4 * h2) = o4;
    }
  if (h2 == 0) {
    size_t mi = ((size_t)z * T_TOK + qw) * NH + hh;
    Mp[mi] = m;
    Lp[mi] = lf;
  }
}

// ---------------- combine KV-split partials (log2-domain maxes) ----------------
__global__ __launch_bounds__(256) void combine(const float* __restrict__ Op,
                                               const float* __restrict__ Mp,
                                               const float* __restrict__ Lp,
                                               unsigned short* __restrict__ Ob) {
  int idx = blockIdx.x * 256 + threadIdx.x;  // T*256 total (4 floats each)
  int t = idx >> 8;
  int q4 = (idx & 255) * 4;  // within [HID): h*64 + d
  int h = q4 >> 6, d = q4 & 63;
  float mz[KVSPLIT], lz[KVSPLIT];
  float ms = -INFINITY;
  #pragma unroll
  for (int zz = 0; zz < KVSPLIT; ++zz) {
    size_t mi = ((size_t)zz * T_TOK + t) * NH + h;
    mz[zz] = Mp[mi];
    lz[zz] = Lp[mi];
    ms = fmaxf(ms, mz[zz]);
  }
  float lsum = 0.f;
  float w[KVSPLIT];
  #pragma unroll
  for (int zz = 0; zz < KVSPLIT; ++zz) {
    w[zz] = __builtin_amdgcn_exp2f(mz[zz] - ms);
    lsum += lz[zz] * w[zz];
  }
  float4 o = {0.f, 0.f, 0.f, 0.f};
  #pragma unroll
  for (int zz = 0; zz < KVSPLIT; ++zz) {
    float4 p = *(const float4*)(Op + (((size_t)zz * T_TOK + t) * NH + h) * HD + d);
    o.x += p.x * w[zz]; o.y += p.y * w[zz];
    o.z += p.z * w[zz]; o.w += p.w * w[zz];
  }
  float inv = 1.f / lsum;
  ushort4 ob;
  ob.x = f2bf(o.x * inv); ob.y = f2bf(o.y * inv);
  ob.z = f2bf(o.z * inv); ob.w = f2bf(o.w * inv);
  *(ushort4*)(Ob + (size_t)t * HID + q4) = ob;
}

extern "C" void kernel_launch(void* const* d_in, const int* in_sizes, int n_in,
                              void* d_out, int out_size, void* d_ws, size_t ws_size,
                              hipStream_t stream) {
  const float* X    = (const float*)d_in[0];
  const float* Wqkv = (const float*)d_in[1];
  const float* Wo   = (const float*)d_in[2];
  const float* mask = (const float*)d_in[3];
  const int*   pos  = (const int*)d_in[4];
  float* out = (float*)d_out;

  char* ws = (char*)d_ws;
  size_t off = 0;
  auto alloc = [&](size_t bytes) {
    char* p = ws + off;
    off += (bytes + 255) & ~(size_t)255;
    return p;
  };
  unsigned short* Xb    = (unsigned short*)alloc((size_t)T_TOK * HID * 2);
  unsigned short* WqkvT = (unsigned short*)alloc((size_t)3 * HID * HID * 2);
  unsigned short* WoT   = (unsigned short*)alloc((size_t)HID * HID * 2);
  unsigned short* Qh    = (unsigned short*)alloc((size_t)NH * T_TOK * HD * 2);
  unsigned short* Kh    = (unsigned short*)alloc((size_t)NH * T_TOK * HD * 2);
  unsigned short* Vt    = (unsigned short*)alloc((size_t)NH * HD * T_TOK * 2);
  unsigned short* Ob    = (unsigned short*)alloc((size_t)T_TOK * HID * 2);
  float*          ctab  = (float*)alloc((size_t)T_TOK * 32 * 4);
  float*          stab  = (float*)alloc((size_t)T_TOK * 32 * 4);
  float*          Mp    = (float*)alloc((size_t)KVSPLIT * T_TOK * NH * 4);
  float*          Lp    = (float*)alloc((size_t)KVSPLIT * T_TOK * NH * 4);
  int*            flags = (int*)alloc((size_t)KVSPLIT * NQB * 4);
  // REGION: bf16 QKV (T x 3H x 2B = 18.9MB) aliased with Opart (KVSPLIT x T x HID f32 = 25.2MB).
  // QKV is dead once rope_v completes, before flash_attn writes Op.
  char*           region = alloc((size_t)KVSPLIT * T_TOK * HID * 4);
  unsigned short* QKVb  = (unsigned short*)region;
  float*          Op    = (float*)region;

  cvt_bf16<<<(T_TOK * HID / 4 + 255) / 256, 256, 0, stream>>>(X, Xb, T_TOK * HID);
  transpose_cvt<<<dim3(3 * HID / 32, HID / 32), 256, 0, stream>>>(Wqkv, WqkvT, HID, 3 * HID);
  transpose_cvt<<<dim3(HID / 32, HID / 32), 256, 0, stream>>>(Wo, WoT, HID, HID);
  rope_table<<<T_TOK * 32 / 256, 256, 0, stream>>>(pos, ctab, stab);
  mask_flags<<<dim3(NQB, KVSPLIT), 1024, 0, stream>>>(mask, flags);

  gemm_bt_bf16<<<dim3(3 * HID / 128, T_TOK / 128), 256, 0, stream>>>(Xb, WqkvT, QKVb, T_TOK, 3 * HID, HID);

  rope_v<<<dim3(T_TOK / 64, NH), 256, 0, stream>>>(QKVb, ctab, stab, Qh, Kh, Vt);

  flash_attn<<<dim3(NQB * NH * KVSPLIT), 256, 0, stream>>>(Qh, Kh, Vt, mask, flags, Op, Mp, Lp);
  combine<<<T_TOK, 256, 0, stream>>>(Op, Mp, Lp, Ob);

  gemm_bt<<<dim3(HID / 128, T_TOK / 128), 256, 0, stream>>>(Ob, WoT, out, T_TOK, HID, HID);
}